// Round 1
// 445.977 us; speedup vs baseline: 1.4241x; 1.4241x over previous
//
#include <hip/hip_runtime.h>
#include <stdint.h>

// ---------- types / helpers ----------
typedef _Float16 h8 __attribute__((ext_vector_type(8)));
typedef _Float16 h4v __attribute__((ext_vector_type(4)));
typedef float f32x4 __attribute__((ext_vector_type(4)));

__device__ __forceinline__ float clampf(float x, float lo, float hi) {
    return fminf(fmaxf(x, lo), hi);
}
__device__ __forceinline__ unsigned short f2bf(float f) {
    unsigned int v;
    __builtin_memcpy(&v, &f, 4);
    v += 0x7FFFu + ((v >> 16) & 1u);
    return (unsigned short)(v >> 16);
}
__device__ __forceinline__ float bf2f(unsigned short u) {
    unsigned int v = ((unsigned int)u) << 16;
    float f;
    __builtin_memcpy(&f, &v, 4);
    return f;
}
// async global->LDS, 16B per lane; lds dest must be wave-uniform base (+ lane*16 implied)
__device__ __forceinline__ void gload16(const _Float16* g, _Float16* l) {
    __builtin_amdgcn_global_load_lds(
        (const __attribute__((address_space(1))) unsigned int*)g,
        (__attribute__((address_space(3))) unsigned int*)l, 16, 0, 0);
}

// ---------- transpose f32 -> f16 (out[c][r] = in[r][c]) ----------
__global__ __launch_bounds__(256) void transpose_f2h(const float* __restrict__ in,
                                                     _Float16* __restrict__ out,
                                                     int rows, int cols) {
    __shared__ _Float16 tile[32][33];
    int bx = blockIdx.x * 32, by = blockIdx.y * 32;
    int tx = threadIdx.x & 31, ty = threadIdx.x >> 5;
    for (int i = ty; i < 32; i += 8)
        tile[i][tx] = (_Float16)in[(size_t)(by + i) * cols + bx + tx];
    __syncthreads();
    for (int i = ty; i < 32; i += 8)
        out[(size_t)(bx + i) * rows + by + tx] = tile[tx][i];
}

// ---------- LN1: f32 x -> f16 normed (one wave per 512-ch row) ----------
__global__ __launch_bounds__(256) void ln1_kernel(const float* __restrict__ x,
                                                  const float* __restrict__ scale,
                                                  _Float16* __restrict__ out) {
    int row = blockIdx.x * 4 + (threadIdx.x >> 6);
    int lane = threadIdx.x & 63;
    const float4* xp = (const float4*)(x + (size_t)row * 512 + lane * 8);
    float4 a = xp[0], b = xp[1];
    const float4* sp = (const float4*)(scale + lane * 8);
    float4 s0v = sp[0], s1v = sp[1];
    float f[8] = {a.x, a.y, a.z, a.w, b.x, b.y, b.z, b.w};
    float sc[8] = {s0v.x, s0v.y, s0v.z, s0v.w, s1v.x, s1v.y, s1v.z, s1v.w};
    float s = 0.f, ss = 0.f;
#pragma unroll
    for (int j = 0; j < 8; j++) { s += f[j]; ss += f[j] * f[j]; }
#pragma unroll
    for (int off = 1; off < 64; off <<= 1) { s += __shfl_xor(s, off); ss += __shfl_xor(ss, off); }
    float mean = s * (1.f / 512.f);
    float var  = ss * (1.f / 512.f) - mean * mean;
    float rs   = rsqrtf(fmaxf(var, 0.f) + 1e-5f);
    union { uint4 u; _Float16 h[8]; } ov;
#pragma unroll
    for (int j = 0; j < 8; j++) ov.h[j] = (_Float16)((f[j] - mean) * rs * sc[j]);
    *(uint4*)(out + (size_t)row * 512 + lane * 8) = ov.u;
}

// ---------- GEMM 128x128 tile (m97-style: unpadded LDS + global_load_lds) ----------
// C[M][:] = A[M][K] * BT[N][K]^T, f16 in, fp32 acc. 4 waves 2x2, 4x4 MFMA tiles/wave.
__global__ __launch_bounds__(256) void gemm128(const _Float16* __restrict__ A,
                                               const _Float16* __restrict__ BT,
                                               _Float16* __restrict__ Cf16,
                                               unsigned short* __restrict__ Cbf16,
                                               const float* __restrict__ bias,
                                               int K, int ldc, float outscale) {
    __shared__ __attribute__((aligned(16))) _Float16 As[128 * 32];
    __shared__ __attribute__((aligned(16))) _Float16 Bs[128 * 32];
    int t = threadIdx.x, w = t >> 6, lane = t & 63;
    int lm = lane & 15, q4 = lane >> 4;
    int m0 = blockIdx.y * 128, n0 = blockIdx.x * 128;
    int wm = (w & 1) * 64, wn = (w >> 1) * 64;
    f32x4 acc[4][4];
#pragma unroll
    for (int i = 0; i < 4; i++)
#pragma unroll
        for (int j = 0; j < 4; j++) acc[i][j] = (f32x4){0.f, 0.f, 0.f, 0.f};

    int sr = t >> 2, sc = (t & 3) * 8;   // sr 0..63, sc {0,8,16,24}
    const _Float16* Ag = A + (size_t)(m0 + sr) * K + sc;
    const _Float16* Bg = BT + (size_t)(n0 + sr) * K + sc;
    _Float16* AsW = As + w * 16 * 32;    // wave-uniform LDS bases (lane*16B implied)
    _Float16* BsW = Bs + w * 16 * 32;

    for (int k0 = 0; k0 < K; k0 += 32) {
        gload16(Ag + k0, AsW);
        gload16(Ag + (size_t)64 * K + k0, AsW + 64 * 32);
        gload16(Bg + k0, BsW);
        gload16(Bg + (size_t)64 * K + k0, BsW + 64 * 32);
        __syncthreads();                 // drains vmcnt -> LDS valid
        h8 af[4], bf[4];
#pragma unroll
        for (int i = 0; i < 4; i++) af[i] = *(const h8*)(As + (wm + i * 16 + lm) * 32 + q4 * 8);
#pragma unroll
        for (int i = 0; i < 4; i++) bf[i] = *(const h8*)(Bs + (wn + i * 16 + lm) * 32 + q4 * 8);
#pragma unroll
        for (int mi = 0; mi < 4; mi++)
#pragma unroll
            for (int ni = 0; ni < 4; ni++)
                acc[mi][ni] = __builtin_amdgcn_mfma_f32_16x16x32_f16(bf[ni], af[mi], acc[mi][ni], 0, 0, 0);
        __syncthreads();                 // all reads done before next iter's loads
    }
#pragma unroll
    for (int mi = 0; mi < 4; mi++) {
        int row = m0 + wm + mi * 16 + lm;
#pragma unroll
        for (int ni = 0; ni < 4; ni++) {
            int col0 = n0 + wn + ni * 16 + q4 * 4;
            float bv[4] = {0.f, 0.f, 0.f, 0.f};
            if (bias) { float4 b4 = *(const float4*)(bias + col0); bv[0]=b4.x; bv[1]=b4.y; bv[2]=b4.z; bv[3]=b4.w; }
            if (Cf16) {
                h4v o;
#pragma unroll
                for (int r = 0; r < 4; r++) o[r] = (_Float16)(acc[mi][ni][r] * outscale + bv[r]);
                *(h4v*)(Cf16 + (size_t)row * ldc + col0) = o;
            } else {
                ushort4 o;
                o.x = f2bf(acc[mi][ni][0] * outscale + bv[0]);
                o.y = f2bf(acc[mi][ni][1] * outscale + bv[1]);
                o.z = f2bf(acc[mi][ni][2] * outscale + bv[2]);
                o.w = f2bf(acc[mi][ni][3] * outscale + bv[3]);
                *(ushort4*)(Cbf16 + (size_t)row * ldc + col0) = o;
            }
        }
    }
}

// ---------- kv transpose + exp(k) + S partials ----------
// in: kvc [8192][1024] f16 (k at col h*64+d, v at col 512+h*64+e), rows = b_local*1024 + n_local
// out: ekT[(b*8+h)*64+d][1024 n], vT[(b*8+h)*64+e][1024 n], Sbuf[bh][d] += sum ek
__global__ __launch_bounds__(256) void kv_texp(const _Float16* __restrict__ kvc,
                                               _Float16* __restrict__ ekT,
                                               _Float16* __restrict__ vT,
                                               float* __restrict__ Sbuf) {
    __shared__ _Float16 tile[64][72];
    int t = threadIdx.x;
    int n0 = blockIdx.x * 64, c0 = blockIdx.y * 64;
    int r = t >> 3, cs8 = (t & 7) * 8;
#pragma unroll
    for (int p = 0; p < 2; p++) {
        int rr = p * 32 + r;
        *(uint4*)(&tile[rr][cs8]) = *(const uint4*)(kvc + (size_t)(n0 + rr) * 1024 + c0 + cs8);
    }
    __syncthreads();
    int bl = n0 >> 10;          // batch index within chunk (tiles never straddle: 64 | 1024)
    int nl0 = n0 & 1023;
    bool isK = (c0 < 512);
#pragma unroll
    for (int p = 0; p < 2; p++) {
        int oc = p * 32 + r;
        int c = c0 + oc;
        int h = (c >> 6) & 7, de = c & 63;
        union { uint4 u; _Float16 hh[8]; } o;
        if (isK) {
            float ssum = 0.f;
#pragma unroll
            for (int j = 0; j < 8; j++) {
                float ek = __expf(clampf((float)tile[cs8 + j][oc], -30.f, 30.f));
                _Float16 e16 = (_Float16)ek;
                o.hh[j] = e16;
                ssum += (float)e16;     // sum the f16-rounded value the GEMM will use
            }
#pragma unroll
            for (int off = 1; off < 8; off <<= 1) ssum += __shfl_xor(ssum, off); // 8 lanes share oc
            *(uint4*)(ekT + ((size_t)(bl * 8 + h) * 64 + de) * 1024 + nl0 + cs8) = o.u;
            if ((t & 7) == 0) atomicAdd(&Sbuf[(bl * 8 + h) * 64 + de], ssum);
        } else {
#pragma unroll
            for (int j = 0; j < 8; j++) o.hh[j] = tile[cs8 + j][oc];
            *(uint4*)(vT + ((size_t)(bl * 8 + h) * 64 + de) * 1024 + nl0 + cs8) = o.u;
        }
    }
}

// ---------- ctx GEMM: part[ks][bh][d][e] = sum_{n in slice} ekT[bh][d][n] * vT[bh][e][n] ----------
// grid (64 bh, 4 kslice); 4 waves: wave w -> d-rows w*16..+15, all 64 e
__global__ __launch_bounds__(256) void ctx_gemm(const _Float16* __restrict__ ekT,
                                                const _Float16* __restrict__ vT,
                                                float* __restrict__ part) {
    __shared__ __attribute__((aligned(16))) _Float16 As[64 * 32];
    __shared__ __attribute__((aligned(16))) _Float16 Bs[64 * 32];
    int t = threadIdx.x, w = t >> 6, lane = t & 63;
    int lm = lane & 15, q4 = lane >> 4;
    int bhl = blockIdx.x, ks = blockIdx.y;
    int sr = t >> 2, sc = (t & 3) * 8;
    const _Float16* Ag = ekT + (size_t)bhl * 64 * 1024 + (size_t)sr * 1024 + ks * 256 + sc;
    const _Float16* Bg = vT  + (size_t)bhl * 64 * 1024 + (size_t)sr * 1024 + ks * 256 + sc;
    _Float16* AsW = As + w * 16 * 32;
    _Float16* BsW = Bs + w * 16 * 32;
    f32x4 acc[4];
#pragma unroll
    for (int i = 0; i < 4; i++) acc[i] = (f32x4){0.f, 0.f, 0.f, 0.f};

    for (int k0 = 0; k0 < 256; k0 += 32) {
        gload16(Ag + k0, AsW);
        gload16(Bg + k0, BsW);
        __syncthreads();
        h8 af = *(const h8*)(As + (w * 16 + lm) * 32 + q4 * 8);
#pragma unroll
        for (int nt = 0; nt < 4; nt++) {
            h8 bf = *(const h8*)(Bs + (nt * 16 + lm) * 32 + q4 * 8);
            acc[nt] = __builtin_amdgcn_mfma_f32_16x16x32_f16(bf, af, acc[nt], 0, 0, 0);
        }
        __syncthreads();
    }
    float* dst = part + ((size_t)ks * 64 + bhl) * 4096 + (w * 16 + lm) * 64;
#pragma unroll
    for (int nt = 0; nt < 4; nt++)
        *(f32x4*)(dst + nt * 16 + q4 * 4) = acc[nt];
}

// ---------- fused q-softmax + PV via MFMA ----------
// attn[n][h*64+e] = sum_d (softmax_d(q)/8)[d] * (ctx[d][e]*invS[d])
// grid (8 ntiles, 64 bh); block 256 = 4 waves, each wave 2 m-tiles of 16 rows -> 128 rows/block.
// A fragments (qn) loaded straight from global in MFMA layout; B (csT) staged once in LDS.
__global__ __launch_bounds__(256) void attnout_mfma(const _Float16* __restrict__ qbuf,
                                                    const float* __restrict__ part,
                                                    const float* __restrict__ Sbuf,
                                                    _Float16* __restrict__ attn) {
    __shared__ _Float16 csT[64][72];     // csT[e][d], padded: 144B row stride (16B-aligned)
    __shared__ float invS[64];
    int t = threadIdx.x, w = t >> 6, lane = t & 63;
    int lm = lane & 15, q4 = lane >> 4;
    int bhl = blockIdx.y;                // b_local*8 + h
    int b = bhl >> 3, h = bhl & 7;
    int n0 = blockIdx.x * 128;
    if (t < 64) invS[t] = 1.f / Sbuf[bhl * 64 + t];
    __syncthreads();
    // stage summed, invS-scaled, transposed ctx into LDS as f16 (B^T layout)
    const f32x4* p0 = (const f32x4*)(part + ((size_t)0 * 64 + bhl) * 4096);
    const f32x4* p1 = (const f32x4*)(part + ((size_t)1 * 64 + bhl) * 4096);
    const f32x4* p2 = (const f32x4*)(part + ((size_t)2 * 64 + bhl) * 4096);
    const f32x4* p3 = (const f32x4*)(part + ((size_t)3 * 64 + bhl) * 4096);
    for (int i = t; i < 1024; i += 256) {
        f32x4 v = p0[i] + p1[i] + p2[i] + p3[i];
        int d = i >> 4, e0 = (i & 15) * 4;
        float is = invS[d];
#pragma unroll
        for (int j = 0; j < 4; j++) csT[e0 + j][d] = (_Float16)(v[j] * is);
    }
    __syncthreads();
    // B fragments once per wave: bf[ni][kc] = csT[ni*16+lm][kc*32 + q4*8 .. +7]
    h8 bf[4][2];
#pragma unroll
    for (int ni = 0; ni < 4; ni++)
#pragma unroll
        for (int kc = 0; kc < 2; kc++)
            bf[ni][kc] = *(const h8*)(&csT[ni * 16 + lm][kc * 32 + q4 * 8]);

    f32x4 acc[2][4];
#pragma unroll
    for (int mi = 0; mi < 2; mi++)
#pragma unroll
        for (int ni = 0; ni < 4; ni++) acc[mi][ni] = (f32x4){0.f, 0.f, 0.f, 0.f};

    const size_t qrow_base = ((size_t)b * 1024 + n0 + w * 32) * 512 + h * 64;
#pragma unroll
    for (int mi = 0; mi < 2; mi++) {
        // lane (lm,q4) reads q[row=lm][d=q4*8..+7] and [d=32+q4*8..+7]: A-fragment layout
        const _Float16* qp = qbuf + qrow_base + (size_t)(mi * 16 + lm) * 512 + q4 * 8;
        h8 q0 = *(const h8*)(qp);
        h8 q1 = *(const h8*)(qp + 32);
        float e[16];
        float s = 0.f;
#pragma unroll
        for (int j = 0; j < 8; j++) { e[j] = __expf(clampf((float)q0[j], -30.f, 30.f)); s += e[j]; }
#pragma unroll
        for (int j = 0; j < 8; j++) { e[8 + j] = __expf(clampf((float)q1[j], -30.f, 30.f)); s += e[8 + j]; }
        // row lives in the 4 lanes sharing lm (q4 = 0..3): reduce across lane bits 4,5
        s += __shfl_xor(s, 16);
        s += __shfl_xor(s, 32);
        float r = 1.f / (s * 8.f);       // softmax / sqrt(64)
        h8 a0, a1;
#pragma unroll
        for (int j = 0; j < 8; j++) a0[j] = (_Float16)(e[j] * r);
#pragma unroll
        for (int j = 0; j < 8; j++) a1[j] = (_Float16)(e[8 + j] * r);
#pragma unroll
        for (int ni = 0; ni < 4; ni++) {
            acc[mi][ni] = __builtin_amdgcn_mfma_f32_16x16x32_f16(bf[ni][0], a0, acc[mi][ni], 0, 0, 0);
            acc[mi][ni] = __builtin_amdgcn_mfma_f32_16x16x32_f16(bf[ni][1], a1, acc[mi][ni], 0, 0, 0);
        }
    }
#pragma unroll
    for (int mi = 0; mi < 2; mi++) {
        int n = n0 + w * 32 + mi * 16 + lm;
        size_t obase = ((size_t)b * 1024 + n) * 512 + h * 64;
#pragma unroll
        for (int ni = 0; ni < 4; ni++) {
            h4v o;
#pragma unroll
            for (int r2 = 0; r2 < 4; r2++) o[r2] = (_Float16)acc[mi][ni][r2];
            *(h4v*)(attn + obase + ni * 16 + q4 * 4) = o;
        }
    }
}

// ---------- LN2 + residual: out = LN(proj)*scale + x  (proj bf16, x/out f32) ----------
__global__ __launch_bounds__(256) void ln2_res_kernel(const unsigned short* __restrict__ proj,
                                                      const float* __restrict__ x,
                                                      const float* __restrict__ scale,
                                                      float* __restrict__ out) {
    int row = blockIdx.x * 4 + (threadIdx.x >> 6);
    int lane = threadIdx.x & 63;
    size_t off = (size_t)row * 512 + lane * 8;
    union { uint4 u; unsigned short us[8]; } pv;
    pv.u = *(const uint4*)(proj + off);
    const float4* xp = (const float4*)(x + off);
    float4 xa = xp[0], xb = xp[1];
    const float4* sp = (const float4*)(scale + lane * 8);
    float4 s0v = sp[0], s1v = sp[1];
    float xr[8] = {xa.x, xa.y, xa.z, xa.w, xb.x, xb.y, xb.z, xb.w};
    float sc[8] = {s0v.x, s0v.y, s0v.z, s0v.w, s1v.x, s1v.y, s1v.z, s1v.w};
    float f[8], s = 0.f, ss = 0.f;
#pragma unroll
    for (int j = 0; j < 8; j++) { f[j] = bf2f(pv.us[j]); s += f[j]; ss += f[j] * f[j]; }
#pragma unroll
    for (int o2 = 1; o2 < 64; o2 <<= 1) { s += __shfl_xor(s, o2); ss += __shfl_xor(ss, o2); }
    float mean = s * (1.f / 512.f);
    float var  = ss * (1.f / 512.f) - mean * mean;
    float rs   = rsqrtf(fmaxf(var, 0.f) + 1e-5f);
    float4 o0, o1;
    float* o0p = &o0.x; float* o1p = &o1.x;
#pragma unroll
    for (int j = 0; j < 4; j++) o0p[j] = (f[j] - mean) * rs * sc[j] + xr[j];
#pragma unroll
    for (int j = 0; j < 4; j++) o1p[j] = (f[4 + j] - mean) * rs * sc[4 + j] + xr[4 + j];
    float4* op = (float4*)(out + off);
    op[0] = o0; op[1] = o1;
}

// ---------- launch ----------
extern "C" void kernel_launch(void* const* d_in, const int* in_sizes, int n_in,
                              void* d_out, int out_size, void* d_ws, size_t ws_size,
                              hipStream_t stream) {
    const float* x    = (const float*)d_in[0];
    const float* ln1s = (const float*)d_in[1];
    const float* wqkv = (const float*)d_in[2];
    const float* wout = (const float*)d_in[3];
    const float* bout = (const float*)d_in[4];
    const float* ln2s = (const float*)d_in[5];
    float* out = (float*)d_out;

    char* ws = (char*)d_ws;
    // ws (~38 MB): wqkvT | woutT | ctx_part f32 [4][64][4096] | Sbuf f32 [64][64] | normed f16
    _Float16* wqkvT  = (_Float16*)(ws);                     // 1,572,864
    _Float16* woutT  = (_Float16*)(ws + 1572864);           //   524,288
    float*    part   = (float*)(ws + 2097152);              // 4,194,304
    float*    Sbuf   = (float*)(ws + 6291456);              //    16,384
    _Float16* normed = (_Float16*)(ws + 6356992);           // 33,554,432
    unsigned short* proj = (unsigned short*)(ws + 6356992); // reuses dead normed slot (bf16)
    // d_out (64 MiB) doubles as scratch, all dead before ln2 writes:
    _Float16* attnF = (_Float16*)d_out;                          // [32768][512] f16 : 32 MiB
    _Float16* kvbuf = (_Float16*)((char*)d_out + 33554432);      // chunk [8192][1024] f16 : 16 MiB (later qbuf)
    _Float16* ekT   = (_Float16*)((char*)d_out + 50331648);      // chunk [64*64][1024] f16 : 8 MiB
    _Float16* vT    = (_Float16*)((char*)d_out + 58720256);      // chunk [64*64][1024] f16 : 8 MiB

    const int nb = 8, nchunks = 4;

    transpose_f2h<<<dim3(48, 16), 256, 0, stream>>>(wqkv, wqkvT, 512, 1536);
    transpose_f2h<<<dim3(16, 16), 256, 0, stream>>>(wout, woutT, 512, 512);
    ln1_kernel<<<8192, 256, 0, stream>>>(x, ln1s, normed);

    for (int c = 0; c < nchunks; c++) {
        size_t row0 = (size_t)c * nb * 1024;
        const _Float16* normed_c = normed + row0 * 512;
        hipMemsetAsync(Sbuf, 0, 16384, stream);
        // kv = normed_c . w_qkv[:, 512:1536]   [8192 x 1024]
        gemm128<<<dim3(8, 64), 256, 0, stream>>>(normed_c, wqkvT + 512 * 512,
                                                 kvbuf, nullptr, nullptr, 512, 1024, 1.f);
        kv_texp<<<dim3(128, 16), 256, 0, stream>>>(kvbuf, ekT, vT, Sbuf);
        ctx_gemm<<<dim3(64, 4), 256, 0, stream>>>(ekT, vT, part);
        // q = normed_c . w_qkv[:, 0:512]  (kvbuf now dead -> qbuf)
        gemm128<<<dim3(4, 64), 256, 0, stream>>>(normed_c, wqkvT,
                                                 kvbuf, nullptr, nullptr, 512, 512, 1.f);
        attnout_mfma<<<dim3(8, 64), 256, 0, stream>>>(kvbuf, part, Sbuf, attnF + row0 * 512);
    }

    // proj = attn . w_out^T * (1/1024) + b_out
    gemm128<<<dim3(4, 256), 256, 0, stream>>>(attnF, woutT, nullptr, proj, bout,
                                              512, 512, 1.f / 1024.f);
    ln2_res_kernel<<<8192, 256, 0, stream>>>(proj, x, ln2s, out);
}

// Round 3
// 391.484 us; speedup vs baseline: 1.6223x; 1.1392x over previous
//
#include <hip/hip_runtime.h>
#include <stdint.h>

// ---------- types / helpers ----------
typedef _Float16 h8 __attribute__((ext_vector_type(8)));
typedef _Float16 h4v __attribute__((ext_vector_type(4)));
typedef float f32x4 __attribute__((ext_vector_type(4)));

__device__ __forceinline__ float clampf(float x, float lo, float hi) {
    return fminf(fmaxf(x, lo), hi);
}
__device__ __forceinline__ unsigned short f2bf(float f) {
    unsigned int v;
    __builtin_memcpy(&v, &f, 4);
    v += 0x7FFFu + ((v >> 16) & 1u);
    return (unsigned short)(v >> 16);
}
__device__ __forceinline__ float bf2f(unsigned short u) {
    unsigned int v = ((unsigned int)u) << 16;
    float f;
    __builtin_memcpy(&f, &v, 4);
    return f;
}
// async global->LDS, 16B per lane; lds dest must be wave-uniform base (+ lane*16 implied)
__device__ __forceinline__ void gload16(const _Float16* g, _Float16* l) {
    __builtin_amdgcn_global_load_lds(
        (const __attribute__((address_space(1))) unsigned int*)g,
        (__attribute__((address_space(3))) unsigned int*)l, 16, 0, 0);
}

// ---------- transpose f32 -> f16 (out[c][r] = in[r][c]) ----------
__global__ __launch_bounds__(256) void transpose_f2h(const float* __restrict__ in,
                                                     _Float16* __restrict__ out,
                                                     int rows, int cols) {
    __shared__ _Float16 tile[32][33];
    int bx = blockIdx.x * 32, by = blockIdx.y * 32;
    int tx = threadIdx.x & 31, ty = threadIdx.x >> 5;
    for (int i = ty; i < 32; i += 8)
        tile[i][tx] = (_Float16)in[(size_t)(by + i) * cols + bx + tx];
    __syncthreads();
    for (int i = ty; i < 32; i += 8)
        out[(size_t)(bx + i) * rows + by + tx] = tile[tx][i];
}

// ---------- LN1: f32 x -> f16 normed (one wave per 512-ch row) ----------
__global__ __launch_bounds__(256) void ln1_kernel(const float* __restrict__ x,
                                                  const float* __restrict__ scale,
                                                  _Float16* __restrict__ out) {
    int row = blockIdx.x * 4 + (threadIdx.x >> 6);
    int lane = threadIdx.x & 63;
    const float4* xp = (const float4*)(x + (size_t)row * 512 + lane * 8);
    float4 a = xp[0], b = xp[1];
    const float4* sp = (const float4*)(scale + lane * 8);
    float4 s0v = sp[0], s1v = sp[1];
    float f[8] = {a.x, a.y, a.z, a.w, b.x, b.y, b.z, b.w};
    float sc[8] = {s0v.x, s0v.y, s0v.z, s0v.w, s1v.x, s1v.y, s1v.z, s1v.w};
    float s = 0.f, ss = 0.f;
#pragma unroll
    for (int j = 0; j < 8; j++) { s += f[j]; ss += f[j] * f[j]; }
#pragma unroll
    for (int off = 1; off < 64; off <<= 1) { s += __shfl_xor(s, off); ss += __shfl_xor(ss, off); }
    float mean = s * (1.f / 512.f);
    float var  = ss * (1.f / 512.f) - mean * mean;
    float rs   = rsqrtf(fmaxf(var, 0.f) + 1e-5f);
    union { uint4 u; _Float16 h[8]; } ov;
#pragma unroll
    for (int j = 0; j < 8; j++) ov.h[j] = (_Float16)((f[j] - mean) * rs * sc[j]);
    *(uint4*)(out + (size_t)row * 512 + lane * 8) = ov.u;
}

// ---------- GEMM 128x128 tile (m97-style: unpadded LDS + global_load_lds) ----------
// C[M][:] = A[M][K] * BT[N][K]^T, f16 in, fp32 acc. 4 waves 2x2, 4x4 MFMA tiles/wave.
__global__ __launch_bounds__(256) void gemm128(const _Float16* __restrict__ A,
                                               const _Float16* __restrict__ BT,
                                               _Float16* __restrict__ Cf16,
                                               unsigned short* __restrict__ Cbf16,
                                               const float* __restrict__ bias,
                                               int K, int ldc, float outscale) {
    __shared__ __attribute__((aligned(16))) _Float16 As[128 * 32];
    __shared__ __attribute__((aligned(16))) _Float16 Bs[128 * 32];
    int t = threadIdx.x, w = t >> 6, lane = t & 63;
    int lm = lane & 15, q4 = lane >> 4;
    int m0 = blockIdx.y * 128, n0 = blockIdx.x * 128;
    int wm = (w & 1) * 64, wn = (w >> 1) * 64;
    f32x4 acc[4][4];
#pragma unroll
    for (int i = 0; i < 4; i++)
#pragma unroll
        for (int j = 0; j < 4; j++) acc[i][j] = (f32x4){0.f, 0.f, 0.f, 0.f};

    int sr = t >> 2, sc = (t & 3) * 8;   // sr 0..63, sc {0,8,16,24}
    const _Float16* Ag = A + (size_t)(m0 + sr) * K + sc;
    const _Float16* Bg = BT + (size_t)(n0 + sr) * K + sc;
    _Float16* AsW = As + w * 16 * 32;    // wave-uniform LDS bases (lane*16B implied)
    _Float16* BsW = Bs + w * 16 * 32;

    for (int k0 = 0; k0 < K; k0 += 32) {
        gload16(Ag + k0, AsW);
        gload16(Ag + (size_t)64 * K + k0, AsW + 64 * 32);
        gload16(Bg + k0, BsW);
        gload16(Bg + (size_t)64 * K + k0, BsW + 64 * 32);
        __syncthreads();                 // drains vmcnt -> LDS valid
        h8 af[4], bf[4];
#pragma unroll
        for (int i = 0; i < 4; i++) af[i] = *(const h8*)(As + (wm + i * 16 + lm) * 32 + q4 * 8);
#pragma unroll
        for (int i = 0; i < 4; i++) bf[i] = *(const h8*)(Bs + (wn + i * 16 + lm) * 32 + q4 * 8);
#pragma unroll
        for (int mi = 0; mi < 4; mi++)
#pragma unroll
            for (int ni = 0; ni < 4; ni++)
                acc[mi][ni] = __builtin_amdgcn_mfma_f32_16x16x32_f16(bf[ni], af[mi], acc[mi][ni], 0, 0, 0);
        __syncthreads();                 // all reads done before next iter's loads
    }
#pragma unroll
    for (int mi = 0; mi < 4; mi++) {
        int row = m0 + wm + mi * 16 + lm;
#pragma unroll
        for (int ni = 0; ni < 4; ni++) {
            int col0 = n0 + wn + ni * 16 + q4 * 4;
            float bv[4] = {0.f, 0.f, 0.f, 0.f};
            if (bias) { float4 b4 = *(const float4*)(bias + col0); bv[0]=b4.x; bv[1]=b4.y; bv[2]=b4.z; bv[3]=b4.w; }
            if (Cf16) {
                h4v o;
#pragma unroll
                for (int r = 0; r < 4; r++) o[r] = (_Float16)(acc[mi][ni][r] * outscale + bv[r]);
                *(h4v*)(Cf16 + (size_t)row * ldc + col0) = o;
            } else {
                ushort4 o;
                o.x = f2bf(acc[mi][ni][0] * outscale + bv[0]);
                o.y = f2bf(acc[mi][ni][1] * outscale + bv[1]);
                o.z = f2bf(acc[mi][ni][2] * outscale + bv[2]);
                o.w = f2bf(acc[mi][ni][3] * outscale + bv[3]);
                *(ushort4*)(Cbf16 + (size_t)row * ldc + col0) = o;
            }
        }
    }
}

// ---------- fused kv GEMM + exp + transpose + S partials ----------
// A = normed_c [8192][512], BT = wqkvT kv-rows [1024][512].
// Block: 128 rows(n) x 128 cols(c). K-cols (c<512): write exp(kv) transposed to
// ekT[(bl*8+h)*64+d][1024 n] and atomicAdd S sums; V-cols: write vT transposed.
__global__ __launch_bounds__(256) void gemm_kvexp(const _Float16* __restrict__ A,
                                                  const _Float16* __restrict__ BT,
                                                  _Float16* __restrict__ ekT,
                                                  _Float16* __restrict__ vT,
                                                  float* __restrict__ Sbuf) {
    // smem: As/Bs (16 KB) during K-loop, overlaid by tr[128 c][132 n] (33.8 KB) after
    __shared__ __attribute__((aligned(16))) char smem[128 * 132 * 2];
    _Float16* As = (_Float16*)smem;
    _Float16* Bs = (_Float16*)(smem + 8192);
    _Float16* tr = (_Float16*)smem;
    int t = threadIdx.x, w = t >> 6, lane = t & 63;
    int lm = lane & 15, q4 = lane >> 4;
    int m0 = blockIdx.y * 128, n0 = blockIdx.x * 128;
    int wm = (w & 1) * 64, wn = (w >> 1) * 64;
    f32x4 acc[4][4];
#pragma unroll
    for (int i = 0; i < 4; i++)
#pragma unroll
        for (int j = 0; j < 4; j++) acc[i][j] = (f32x4){0.f, 0.f, 0.f, 0.f};

    int sr = t >> 2, sc = (t & 3) * 8;
    const _Float16* Ag = A + (size_t)(m0 + sr) * 512 + sc;
    const _Float16* Bg = BT + (size_t)(n0 + sr) * 512 + sc;
    _Float16* AsW = As + w * 512;
    _Float16* BsW = Bs + w * 512;

    for (int k0 = 0; k0 < 512; k0 += 32) {
        gload16(Ag + k0, AsW);
        gload16(Ag + (size_t)64 * 512 + k0, AsW + 64 * 32);
        gload16(Bg + k0, BsW);
        gload16(Bg + (size_t)64 * 512 + k0, BsW + 64 * 32);
        __syncthreads();
        h8 af[4], bf[4];
#pragma unroll
        for (int i = 0; i < 4; i++) af[i] = *(const h8*)(As + (wm + i * 16 + lm) * 32 + q4 * 8);
#pragma unroll
        for (int i = 0; i < 4; i++) bf[i] = *(const h8*)(Bs + (wn + i * 16 + lm) * 32 + q4 * 8);
#pragma unroll
        for (int mi = 0; mi < 4; mi++)
#pragma unroll
            for (int ni = 0; ni < 4; ni++)
                acc[mi][ni] = __builtin_amdgcn_mfma_f32_16x16x32_f16(bf[ni], af[mi], acc[mi][ni], 0, 0, 0);
        __syncthreads();
    }
    // epilogue: (exp +) transpose via LDS. tr[c][n], row stride 132 halves (b64-aligned).
    bool isK = (n0 < 512);
#pragma unroll
    for (int mi = 0; mi < 4; mi++) {
        int row = wm + mi * 16 + lm;
#pragma unroll
        for (int ni = 0; ni < 4; ni++) {
            int col0 = wn + ni * 16 + q4 * 4;
            f32x4 v = acc[mi][ni];
#pragma unroll
            for (int r = 0; r < 4; r++) {
                float f = v[r];
                if (isK) f = __expf(clampf(f, -30.f, 30.f));
                tr[(col0 + r) * 132 + row] = (_Float16)f;
            }
        }
    }
    __syncthreads();
    int bl = m0 >> 10, nl0 = m0 & 1023;    // batch-in-chunk; 1024 % 128 == 0, no straddle
    int oc = t >> 1, half = t & 1;         // thread: output row oc (c-dim), 64-n half
    int c = n0 + oc;
    int h = (c >> 6) & 7, de = c & 63;
    _Float16* dst = (isK ? ekT : vT) + ((size_t)(bl * 8 + h) * 64 + de) * 1024 + nl0 + half * 64;
    const _Float16* src = tr + oc * 132 + half * 64;
    float ssum = 0.f;
#pragma unroll
    for (int j = 0; j < 8; j++) {
        h4v u0 = *(const h4v*)(src + j * 8);
        h4v u1 = *(const h4v*)(src + j * 8 + 4);
        if (isK) {
#pragma unroll
            for (int q = 0; q < 4; q++) ssum += (float)u0[q] + (float)u1[q];
        }
        union { struct { h4v a, b; } hh; uint4 u; } uu;
        uu.hh.a = u0; uu.hh.b = u1;
        *(uint4*)(dst + j * 8) = uu.u;
    }
    if (isK) {
        ssum += __shfl_xor(ssum, 1);       // pair covers the row's two 64-n halves
        if ((t & 1) == 0) atomicAdd(&Sbuf[(bl * 8 + h) * 64 + de], ssum);
    }
}

// ---------- ctx GEMM: part[ks][bh][d][e] = sum_{n in slice} ekT[bh][d][n] * vT[bh][e][n] ----------
// grid (64 bh, 4 kslice); 4 waves: wave w -> d-rows w*16..+15, all 64 e
__global__ __launch_bounds__(256) void ctx_gemm(const _Float16* __restrict__ ekT,
                                                const _Float16* __restrict__ vT,
                                                float* __restrict__ part) {
    __shared__ __attribute__((aligned(16))) _Float16 As[64 * 32];
    __shared__ __attribute__((aligned(16))) _Float16 Bs[64 * 32];
    int t = threadIdx.x, w = t >> 6, lane = t & 63;
    int lm = lane & 15, q4 = lane >> 4;
    int bhl = blockIdx.x, ks = blockIdx.y;
    int sr = t >> 2, sc = (t & 3) * 8;
    const _Float16* Ag = ekT + (size_t)bhl * 64 * 1024 + (size_t)sr * 1024 + ks * 256 + sc;
    const _Float16* Bg = vT  + (size_t)bhl * 64 * 1024 + (size_t)sr * 1024 + ks * 256 + sc;
    _Float16* AsW = As + w * 16 * 32;
    _Float16* BsW = Bs + w * 16 * 32;
    f32x4 acc[4];
#pragma unroll
    for (int i = 0; i < 4; i++) acc[i] = (f32x4){0.f, 0.f, 0.f, 0.f};

    for (int k0 = 0; k0 < 256; k0 += 32) {
        gload16(Ag + k0, AsW);
        gload16(Bg + k0, BsW);
        __syncthreads();
        h8 af = *(const h8*)(As + (w * 16 + lm) * 32 + q4 * 8);
#pragma unroll
        for (int nt = 0; nt < 4; nt++) {
            h8 bf = *(const h8*)(Bs + (nt * 16 + lm) * 32 + q4 * 8);
            acc[nt] = __builtin_amdgcn_mfma_f32_16x16x32_f16(bf, af, acc[nt], 0, 0, 0);
        }
        __syncthreads();
    }
    float* dst = part + ((size_t)ks * 64 + bhl) * 4096 + (w * 16 + lm) * 64;
#pragma unroll
    for (int nt = 0; nt < 4; nt++)
        *(f32x4*)(dst + nt * 16 + q4 * 4) = acc[nt];
}

// ---------- fused q GEMM + per-head softmax + PV ----------
// A = normed_c, BT = wqkvT q-rows. Block: 128 rows x 128 cols = 2 complete heads.
// Wave's 64 cols = one head -> softmax sum fully in-wave (shfl_xor 16,32).
// PV: attn[n][h*64+e] = sum_d qn[n][d] * csT[e][d], K=64 MFMA from LDS tiles.
__global__ __launch_bounds__(256) void gemm_qattn(const _Float16* __restrict__ A,
                                                  const _Float16* __restrict__ BT,
                                                  const float* __restrict__ part,
                                                  const float* __restrict__ Sbuf,
                                                  _Float16* __restrict__ attn) {
    // smem: As/Bs (16 KB) during K-loop; then qn[128][132] (33792 B) + csT[2][64][68] (17408 B)
    __shared__ __attribute__((aligned(16))) char smem[33792 + 17408];
    _Float16* As  = (_Float16*)smem;
    _Float16* Bs  = (_Float16*)(smem + 8192);
    _Float16* qn  = (_Float16*)smem;             // [128][132]
    _Float16* csT = (_Float16*)(smem + 33792);   // [2][64][68]
    int t = threadIdx.x, w = t >> 6, lane = t & 63;
    int lm = lane & 15, q4 = lane >> 4;
    int m0 = blockIdx.y * 128, n0 = blockIdx.x * 128;
    int wm = (w & 1) * 64, wn = (w >> 1) * 64;
    f32x4 acc[4][4];
#pragma unroll
    for (int i = 0; i < 4; i++)
#pragma unroll
        for (int j = 0; j < 4; j++) acc[i][j] = (f32x4){0.f, 0.f, 0.f, 0.f};

    int sr = t >> 2, sc = (t & 3) * 8;
    const _Float16* Ag = A + (size_t)(m0 + sr) * 512 + sc;
    const _Float16* Bg = BT + (size_t)(n0 + sr) * 512 + sc;
    _Float16* AsW = As + w * 512;
    _Float16* BsW = Bs + w * 512;

    for (int k0 = 0; k0 < 512; k0 += 32) {
        gload16(Ag + k0, AsW);
        gload16(Ag + (size_t)64 * 512 + k0, AsW + 64 * 32);
        gload16(Bg + k0, BsW);
        gload16(Bg + (size_t)64 * 512 + k0, BsW + 64 * 32);
        __syncthreads();
        h8 af[4], bf[4];
#pragma unroll
        for (int i = 0; i < 4; i++) af[i] = *(const h8*)(As + (wm + i * 16 + lm) * 32 + q4 * 8);
#pragma unroll
        for (int i = 0; i < 4; i++) bf[i] = *(const h8*)(Bs + (wn + i * 16 + lm) * 32 + q4 * 8);
#pragma unroll
        for (int mi = 0; mi < 4; mi++)
#pragma unroll
            for (int ni = 0; ni < 4; ni++)
                acc[mi][ni] = __builtin_amdgcn_mfma_f32_16x16x32_f16(bf[ni], af[mi], acc[mi][ni], 0, 0, 0);
        __syncthreads();
    }
    // per-row softmax over this wave's head (64 cols): exp in-place, row sums via shfl over q4
    float rws[4];
#pragma unroll
    for (int mi = 0; mi < 4; mi++) {
        float s = 0.f;
#pragma unroll
        for (int ni = 0; ni < 4; ni++) {
            f32x4 e;
#pragma unroll
            for (int r = 0; r < 4; r++) {
                e[r] = __expf(clampf(acc[mi][ni][r], -30.f, 30.f));
                s += e[r];
            }
            acc[mi][ni] = e;
        }
        s += __shfl_xor(s, 16);
        s += __shfl_xor(s, 32);
        rws[mi] = 1.f / (s * 8.f);           // softmax / sqrt(64)
    }
    // write qn tile (f16) to LDS (overlays As/Bs; safe after final K-loop barrier)
#pragma unroll
    for (int mi = 0; mi < 4; mi++) {
        int row = wm + mi * 16 + lm;
        float r = rws[mi];
#pragma unroll
        for (int ni = 0; ni < 4; ni++) {
            int col0 = wn + ni * 16 + q4 * 4;
            h4v o;
#pragma unroll
            for (int j = 0; j < 4; j++) o[j] = (_Float16)(acc[mi][ni][j] * r);
            *(h4v*)(qn + row * 132 + col0) = o;
        }
    }
    // stage csT[hh][e][d] = (sum_ks part[ks][bh])[d][e] * invS[d]  (f16, B^T layout)
    int bl = m0 >> 10;
    int head0 = n0 >> 6;
#pragma unroll
    for (int hh2 = 0; hh2 < 2; hh2++) {
        int bh = bl * 8 + head0 + hh2;
        const f32x4* p0 = (const f32x4*)(part + ((size_t)0 * 64 + bh) * 4096);
        const f32x4* p1 = (const f32x4*)(part + ((size_t)1 * 64 + bh) * 4096);
        const f32x4* p2 = (const f32x4*)(part + ((size_t)2 * 64 + bh) * 4096);
        const f32x4* p3 = (const f32x4*)(part + ((size_t)3 * 64 + bh) * 4096);
        for (int i = t; i < 1024; i += 256) {
            f32x4 v = p0[i] + p1[i] + p2[i] + p3[i];
            int d = i >> 4, e0 = (i & 15) * 4;
            float is = 1.f / Sbuf[bh * 64 + d];
#pragma unroll
            for (int j = 0; j < 4; j++)
                csT[hh2 * 64 * 68 + (e0 + j) * 68 + d] = (_Float16)(v[j] * is);
        }
    }
    __syncthreads();
    // PV: per wave: rows wm..+63 of its head hh = w>>1, e-cols wn&63 (== output cols)
    int hh = w >> 1;
    f32x4 acc2[4][4];
#pragma unroll
    for (int i = 0; i < 4; i++)
#pragma unroll
        for (int j = 0; j < 4; j++) acc2[i][j] = (f32x4){0.f, 0.f, 0.f, 0.f};
#pragma unroll
    for (int kc = 0; kc < 2; kc++) {
        h8 af[4], bf[4];
#pragma unroll
        for (int mi = 0; mi < 4; mi++) {
            const _Float16* p = qn + (wm + mi * 16 + lm) * 132 + hh * 64 + kc * 32 + q4 * 8;
            h4v lo = *(const h4v*)p;
            h4v hi = *(const h4v*)(p + 4);
            h8 a;
#pragma unroll
            for (int j = 0; j < 4; j++) { a[j] = lo[j]; a[4 + j] = hi[j]; }
            af[mi] = a;
        }
#pragma unroll
        for (int ni = 0; ni < 4; ni++) {
            const _Float16* p = csT + hh * 64 * 68 + (ni * 16 + lm) * 68 + kc * 32 + q4 * 8;
            h4v lo = *(const h4v*)p;
            h4v hi = *(const h4v*)(p + 4);
            h8 b;
#pragma unroll
            for (int j = 0; j < 4; j++) { b[j] = lo[j]; b[4 + j] = hi[j]; }
            bf[ni] = b;
        }
#pragma unroll
        for (int mi = 0; mi < 4; mi++)
#pragma unroll
            for (int ni = 0; ni < 4; ni++)
                acc2[mi][ni] = __builtin_amdgcn_mfma_f32_16x16x32_f16(bf[ni], af[mi], acc2[mi][ni], 0, 0, 0);
    }
#pragma unroll
    for (int mi = 0; mi < 4; mi++) {
        int row = m0 + wm + mi * 16 + lm;
#pragma unroll
        for (int ni = 0; ni < 4; ni++) {
            int col0 = n0 + wn + ni * 16 + q4 * 4;   // == h*64 + e directly
            h4v o;
#pragma unroll
            for (int r = 0; r < 4; r++) o[r] = (_Float16)acc2[mi][ni][r];
            *(h4v*)(attn + (size_t)row * 512 + col0) = o;
        }
    }
}

// ---------- LN2 + residual: out = LN(proj)*scale + x  (proj bf16, x/out f32) ----------
__global__ __launch_bounds__(256) void ln2_res_kernel(const unsigned short* __restrict__ proj,
                                                      const float* __restrict__ x,
                                                      const float* __restrict__ scale,
                                                      float* __restrict__ out) {
    int row = blockIdx.x * 4 + (threadIdx.x >> 6);
    int lane = threadIdx.x & 63;
    size_t off = (size_t)row * 512 + lane * 8;
    union { uint4 u; unsigned short us[8]; } pv;
    pv.u = *(const uint4*)(proj + off);
    const float4* xp = (const float4*)(x + off);
    float4 xa = xp[0], xb = xp[1];
    const float4* sp = (const float4*)(scale + lane * 8);
    float4 s0v = sp[0], s1v = sp[1];
    float xr[8] = {xa.x, xa.y, xa.z, xa.w, xb.x, xb.y, xb.z, xb.w};
    float sc[8] = {s0v.x, s0v.y, s0v.z, s0v.w, s1v.x, s1v.y, s1v.z, s1v.w};
    float f[8], s = 0.f, ss = 0.f;
#pragma unroll
    for (int j = 0; j < 8; j++) { f[j] = bf2f(pv.us[j]); s += f[j]; ss += f[j] * f[j]; }
#pragma unroll
    for (int o2 = 1; o2 < 64; o2 <<= 1) { s += __shfl_xor(s, o2); ss += __shfl_xor(ss, o2); }
    float mean = s * (1.f / 512.f);
    float var  = ss * (1.f / 512.f) - mean * mean;
    float rs   = rsqrtf(fmaxf(var, 0.f) + 1e-5f);
    float4 o0, o1;
    float* o0p = &o0.x; float* o1p = &o1.x;
#pragma unroll
    for (int j = 0; j < 4; j++) o0p[j] = (f[j] - mean) * rs * sc[j] + xr[j];
#pragma unroll
    for (int j = 0; j < 4; j++) o1p[j] = (f[4 + j] - mean) * rs * sc[4 + j] + xr[4 + j];
    float4* op = (float4*)(out + off);
    op[0] = o0; op[1] = o1;
}

// ---------- launch ----------
extern "C" void kernel_launch(void* const* d_in, const int* in_sizes, int n_in,
                              void* d_out, int out_size, void* d_ws, size_t ws_size,
                              hipStream_t stream) {
    const float* x    = (const float*)d_in[0];
    const float* ln1s = (const float*)d_in[1];
    const float* wqkv = (const float*)d_in[2];
    const float* wout = (const float*)d_in[3];
    const float* bout = (const float*)d_in[4];
    const float* ln2s = (const float*)d_in[5];
    float* out = (float*)d_out;

    char* ws = (char*)d_ws;
    // ws (~38 MB): wqkvT | woutT | ctx_part f32 [4][64][4096] | Sbuf f32 [64][64] | normed f16
    _Float16* wqkvT  = (_Float16*)(ws);                     // 1,572,864
    _Float16* woutT  = (_Float16*)(ws + 1572864);           //   524,288
    float*    part   = (float*)(ws + 2097152);              // 4,194,304
    float*    Sbuf   = (float*)(ws + 6291456);              //    16,384
    _Float16* normed = (_Float16*)(ws + 6356992);           // 33,554,432
    unsigned short* proj = (unsigned short*)(ws + 6356992); // reuses dead normed slot (bf16)
    // d_out (64 MiB) doubles as scratch, all dead before ln2 writes:
    _Float16* attnF = (_Float16*)d_out;                          // [32768][512] f16 : 32 MiB
    _Float16* ekT   = (_Float16*)((char*)d_out + 50331648);      // chunk [64*64][1024] f16 : 8 MiB
    _Float16* vT    = (_Float16*)((char*)d_out + 58720256);      // chunk [64*64][1024] f16 : 8 MiB

    const int nb = 8, nchunks = 4;

    transpose_f2h<<<dim3(48, 16), 256, 0, stream>>>(wqkv, wqkvT, 512, 1536);
    transpose_f2h<<<dim3(16, 16), 256, 0, stream>>>(wout, woutT, 512, 512);
    ln1_kernel<<<8192, 256, 0, stream>>>(x, ln1s, normed);

    for (int c = 0; c < nchunks; c++) {
        size_t row0 = (size_t)c * nb * 1024;
        const _Float16* normed_c = normed + row0 * 512;
        hipMemsetAsync(Sbuf, 0, 16384, stream);
        // kv = normed_c . w_qkv[:, 512:1536] with fused exp/transpose/S
        gemm_kvexp<<<dim3(8, 64), 256, 0, stream>>>(normed_c, wqkvT + 512 * 512,
                                                    ekT, vT, Sbuf);
        ctx_gemm<<<dim3(64, 4), 256, 0, stream>>>(ekT, vT, part);
        // q = normed_c . w_qkv[:, 0:512] with fused softmax + PV
        gemm_qattn<<<dim3(4, 64), 256, 0, stream>>>(normed_c, wqkvT, part, Sbuf,
                                                    attnF + row0 * 512);
    }

    // proj = attn . w_out^T * (1/1024) + b_out
    gemm128<<<dim3(4, 256), 256, 0, stream>>>(attnF, woutT, nullptr, proj, bout,
                                              512, 512, 1.f / 1024.f);
    ln2_res_kernel<<<8192, 256, 0, stream>>>(proj, x, ln2s, out);
}

// Round 4
// 377.825 us; speedup vs baseline: 1.6809x; 1.0362x over previous
//
#include <hip/hip_runtime.h>
#include <stdint.h>

// ---------- types / helpers ----------
typedef _Float16 h8 __attribute__((ext_vector_type(8)));
typedef _Float16 h4v __attribute__((ext_vector_type(4)));
typedef float f32x4 __attribute__((ext_vector_type(4)));

__device__ __forceinline__ float clampf(float x, float lo, float hi) {
    return fminf(fmaxf(x, lo), hi);
}
// async global->LDS, 16B per lane; lds dest must be wave-uniform base (+ lane*16 implied)
__device__ __forceinline__ void gload16(const _Float16* g, _Float16* l) {
    __builtin_amdgcn_global_load_lds(
        (const __attribute__((address_space(1))) unsigned int*)g,
        (__attribute__((address_space(3))) unsigned int*)l, 16, 0, 0);
}

// ---------- transpose f32 -> f16 (out[c][r] = in[r][c]) ----------
__global__ __launch_bounds__(256) void transpose_f2h(const float* __restrict__ in,
                                                     _Float16* __restrict__ out,
                                                     int rows, int cols) {
    __shared__ _Float16 tile[32][33];
    int bx = blockIdx.x * 32, by = blockIdx.y * 32;
    int tx = threadIdx.x & 31, ty = threadIdx.x >> 5;
    for (int i = ty; i < 32; i += 8)
        tile[i][tx] = (_Float16)in[(size_t)(by + i) * cols + bx + tx];
    __syncthreads();
    for (int i = ty; i < 32; i += 8)
        out[(size_t)(bx + i) * rows + by + tx] = tile[tx][i];
}

// ---------- LN1: f32 x -> f16 normed (one wave per 512-ch row) ----------
__global__ __launch_bounds__(256) void ln1_kernel(const float* __restrict__ x,
                                                  const float* __restrict__ scale,
                                                  _Float16* __restrict__ out) {
    int row = blockIdx.x * 4 + (threadIdx.x >> 6);
    int lane = threadIdx.x & 63;
    const float4* xp = (const float4*)(x + (size_t)row * 512 + lane * 8);
    float4 a = xp[0], b = xp[1];
    const float4* sp = (const float4*)(scale + lane * 8);
    float4 s0v = sp[0], s1v = sp[1];
    float f[8] = {a.x, a.y, a.z, a.w, b.x, b.y, b.z, b.w};
    float sc[8] = {s0v.x, s0v.y, s0v.z, s0v.w, s1v.x, s1v.y, s1v.z, s1v.w};
    float s = 0.f, ss = 0.f;
#pragma unroll
    for (int j = 0; j < 8; j++) { s += f[j]; ss += f[j] * f[j]; }
#pragma unroll
    for (int off = 1; off < 64; off <<= 1) { s += __shfl_xor(s, off); ss += __shfl_xor(ss, off); }
    float mean = s * (1.f / 512.f);
    float var  = ss * (1.f / 512.f) - mean * mean;
    float rs   = rsqrtf(fmaxf(var, 0.f) + 1e-5f);
    union { uint4 u; _Float16 h[8]; } ov;
#pragma unroll
    for (int j = 0; j < 8; j++) ov.h[j] = (_Float16)((f[j] - mean) * rs * sc[j]);
    *(uint4*)(out + (size_t)row * 512 + lane * 8) = ov.u;
}

// ---------- fused kv GEMM + exp + transpose + S partials ----------
// A = normed_c [8192][512], BT = wqkvT kv-rows [1024][512].
// Block: 128 rows(n) x 128 cols(c). K-cols (c<512): write exp(kv) transposed to
// ekT[(bl*8+h)*64+d][1024 n] and atomicAdd S sums; V-cols: write vT transposed.
__global__ __launch_bounds__(256) void gemm_kvexp(const _Float16* __restrict__ A,
                                                  const _Float16* __restrict__ BT,
                                                  _Float16* __restrict__ ekT,
                                                  _Float16* __restrict__ vT,
                                                  float* __restrict__ Sbuf) {
    // smem: As/Bs (16 KB) during K-loop, overlaid by tr[128 c][132 n] (33.8 KB) after
    __shared__ __attribute__((aligned(16))) char smem[128 * 132 * 2];
    _Float16* As = (_Float16*)smem;
    _Float16* Bs = (_Float16*)(smem + 8192);
    _Float16* tr = (_Float16*)smem;
    int t = threadIdx.x, w = t >> 6, lane = t & 63;
    int lm = lane & 15, q4 = lane >> 4;
    int m0 = blockIdx.y * 128, n0 = blockIdx.x * 128;
    int wm = (w & 1) * 64, wn = (w >> 1) * 64;
    f32x4 acc[4][4];
#pragma unroll
    for (int i = 0; i < 4; i++)
#pragma unroll
        for (int j = 0; j < 4; j++) acc[i][j] = (f32x4){0.f, 0.f, 0.f, 0.f};

    int sr = t >> 2, sc = (t & 3) * 8;
    const _Float16* Ag = A + (size_t)(m0 + sr) * 512 + sc;
    const _Float16* Bg = BT + (size_t)(n0 + sr) * 512 + sc;
    _Float16* AsW = As + w * 512;
    _Float16* BsW = Bs + w * 512;

    for (int k0 = 0; k0 < 512; k0 += 32) {
        gload16(Ag + k0, AsW);
        gload16(Ag + (size_t)64 * 512 + k0, AsW + 64 * 32);
        gload16(Bg + k0, BsW);
        gload16(Bg + (size_t)64 * 512 + k0, BsW + 64 * 32);
        __syncthreads();
        h8 af[4], bf[4];
#pragma unroll
        for (int i = 0; i < 4; i++) af[i] = *(const h8*)(As + (wm + i * 16 + lm) * 32 + q4 * 8);
#pragma unroll
        for (int i = 0; i < 4; i++) bf[i] = *(const h8*)(Bs + (wn + i * 16 + lm) * 32 + q4 * 8);
#pragma unroll
        for (int mi = 0; mi < 4; mi++)
#pragma unroll
            for (int ni = 0; ni < 4; ni++)
                acc[mi][ni] = __builtin_amdgcn_mfma_f32_16x16x32_f16(bf[ni], af[mi], acc[mi][ni], 0, 0, 0);
        __syncthreads();
    }
    // epilogue: (exp +) transpose via LDS. tr[c][n], row stride 132 halves (b64-aligned).
    bool isK = (n0 < 512);
#pragma unroll
    for (int mi = 0; mi < 4; mi++) {
        int row = wm + mi * 16 + lm;
#pragma unroll
        for (int ni = 0; ni < 4; ni++) {
            int col0 = wn + ni * 16 + q4 * 4;
            f32x4 v = acc[mi][ni];
#pragma unroll
            for (int r = 0; r < 4; r++) {
                float f = v[r];
                if (isK) f = __expf(clampf(f, -30.f, 30.f));
                tr[(col0 + r) * 132 + row] = (_Float16)f;
            }
        }
    }
    __syncthreads();
    int bl = m0 >> 10, nl0 = m0 & 1023;    // batch-in-chunk; 1024 % 128 == 0, no straddle
    int oc = t >> 1, half = t & 1;         // thread: output row oc (c-dim), 64-n half
    int c = n0 + oc;
    int h = (c >> 6) & 7, de = c & 63;
    _Float16* dst = (isK ? ekT : vT) + ((size_t)(bl * 8 + h) * 64 + de) * 1024 + nl0 + half * 64;
    const _Float16* src = tr + oc * 132 + half * 64;
    float ssum = 0.f;
#pragma unroll
    for (int j = 0; j < 8; j++) {
        h4v u0 = *(const h4v*)(src + j * 8);
        h4v u1 = *(const h4v*)(src + j * 8 + 4);
        if (isK) {
#pragma unroll
            for (int q = 0; q < 4; q++) ssum += (float)u0[q] + (float)u1[q];
        }
        union { struct { h4v a, b; } hh; uint4 u; } uu;
        uu.hh.a = u0; uu.hh.b = u1;
        *(uint4*)(dst + j * 8) = uu.u;
    }
    if (isK) {
        ssum += __shfl_xor(ssum, 1);       // pair covers the row's two 64-n halves
        if ((t & 1) == 0) atomicAdd(&Sbuf[(bl * 8 + h) * 64 + de], ssum);
    }
}

// ---------- ctx GEMM: part[ks][bh][d][e] = sum_{n in slice} ekT[bh][d][n] * vT[bh][e][n] ----------
// grid (64 bh, 4 kslice); 4 waves: wave w -> d-rows w*16..+15, all 64 e
__global__ __launch_bounds__(256) void ctx_gemm(const _Float16* __restrict__ ekT,
                                                const _Float16* __restrict__ vT,
                                                float* __restrict__ part) {
    __shared__ __attribute__((aligned(16))) _Float16 As[64 * 32];
    __shared__ __attribute__((aligned(16))) _Float16 Bs[64 * 32];
    int t = threadIdx.x, w = t >> 6, lane = t & 63;
    int lm = lane & 15, q4 = lane >> 4;
    int bhl = blockIdx.x, ks = blockIdx.y;
    int sr = t >> 2, sc = (t & 3) * 8;
    const _Float16* Ag = ekT + (size_t)bhl * 64 * 1024 + (size_t)sr * 1024 + ks * 256 + sc;
    const _Float16* Bg = vT  + (size_t)bhl * 64 * 1024 + (size_t)sr * 1024 + ks * 256 + sc;
    _Float16* AsW = As + w * 16 * 32;
    _Float16* BsW = Bs + w * 16 * 32;
    f32x4 acc[4];
#pragma unroll
    for (int i = 0; i < 4; i++) acc[i] = (f32x4){0.f, 0.f, 0.f, 0.f};

    for (int k0 = 0; k0 < 256; k0 += 32) {
        gload16(Ag + k0, AsW);
        gload16(Bg + k0, BsW);
        __syncthreads();
        h8 af = *(const h8*)(As + (w * 16 + lm) * 32 + q4 * 8);
#pragma unroll
        for (int nt = 0; nt < 4; nt++) {
            h8 bf = *(const h8*)(Bs + (nt * 16 + lm) * 32 + q4 * 8);
            acc[nt] = __builtin_amdgcn_mfma_f32_16x16x32_f16(bf, af, acc[nt], 0, 0, 0);
        }
        __syncthreads();
    }
    float* dst = part + ((size_t)ks * 64 + bhl) * 4096 + (w * 16 + lm) * 64;
#pragma unroll
    for (int nt = 0; nt < 4; nt++)
        *(f32x4*)(dst + nt * 16 + q4 * 4) = acc[nt];
}

// ---------- fused q GEMM + per-head softmax + PV ----------
// A = normed_c, BT = wqkvT q-rows. Block: 128 rows x 128 cols = 2 complete heads.
// Wave's 64 cols = one head -> softmax sum fully in-wave (shfl_xor 16,32).
// PV: attn[n][h*64+e] = sum_d qn[n][d] * csT[e][d], K=64 MFMA from LDS tiles.
__global__ __launch_bounds__(256) void gemm_qattn(const _Float16* __restrict__ A,
                                                  const _Float16* __restrict__ BT,
                                                  const float* __restrict__ part,
                                                  const float* __restrict__ Sbuf,
                                                  _Float16* __restrict__ attn) {
    // smem: As/Bs (16 KB) during K-loop; then qn[128][132] (33792 B) + csT[2][64][68] (17408 B)
    __shared__ __attribute__((aligned(16))) char smem[33792 + 17408];
    _Float16* As  = (_Float16*)smem;
    _Float16* Bs  = (_Float16*)(smem + 8192);
    _Float16* qn  = (_Float16*)smem;             // [128][132]
    _Float16* csT = (_Float16*)(smem + 33792);   // [2][64][68]
    int t = threadIdx.x, w = t >> 6, lane = t & 63;
    int lm = lane & 15, q4 = lane >> 4;
    int m0 = blockIdx.y * 128, n0 = blockIdx.x * 128;
    int wm = (w & 1) * 64, wn = (w >> 1) * 64;
    f32x4 acc[4][4];
#pragma unroll
    for (int i = 0; i < 4; i++)
#pragma unroll
        for (int j = 0; j < 4; j++) acc[i][j] = (f32x4){0.f, 0.f, 0.f, 0.f};

    int sr = t >> 2, sc = (t & 3) * 8;
    const _Float16* Ag = A + (size_t)(m0 + sr) * 512 + sc;
    const _Float16* Bg = BT + (size_t)(n0 + sr) * 512 + sc;
    _Float16* AsW = As + w * 512;
    _Float16* BsW = Bs + w * 512;

    for (int k0 = 0; k0 < 512; k0 += 32) {
        gload16(Ag + k0, AsW);
        gload16(Ag + (size_t)64 * 512 + k0, AsW + 64 * 32);
        gload16(Bg + k0, BsW);
        gload16(Bg + (size_t)64 * 512 + k0, BsW + 64 * 32);
        __syncthreads();
        h8 af[4], bf[4];
#pragma unroll
        for (int i = 0; i < 4; i++) af[i] = *(const h8*)(As + (wm + i * 16 + lm) * 32 + q4 * 8);
#pragma unroll
        for (int i = 0; i < 4; i++) bf[i] = *(const h8*)(Bs + (wn + i * 16 + lm) * 32 + q4 * 8);
#pragma unroll
        for (int mi = 0; mi < 4; mi++)
#pragma unroll
            for (int ni = 0; ni < 4; ni++)
                acc[mi][ni] = __builtin_amdgcn_mfma_f32_16x16x32_f16(bf[ni], af[mi], acc[mi][ni], 0, 0, 0);
        __syncthreads();
    }
    // per-row softmax over this wave's head (64 cols): exp in-place, row sums via shfl over q4
    float rws[4];
#pragma unroll
    for (int mi = 0; mi < 4; mi++) {
        float s = 0.f;
#pragma unroll
        for (int ni = 0; ni < 4; ni++) {
            f32x4 e;
#pragma unroll
            for (int r = 0; r < 4; r++) {
                e[r] = __expf(clampf(acc[mi][ni][r], -30.f, 30.f));
                s += e[r];
            }
            acc[mi][ni] = e;
        }
        s += __shfl_xor(s, 16);
        s += __shfl_xor(s, 32);
        rws[mi] = 1.f / (s * 8.f);           // softmax / sqrt(64)
    }
    // write qn tile (f16) to LDS (overlays As/Bs; safe after final K-loop barrier)
#pragma unroll
    for (int mi = 0; mi < 4; mi++) {
        int row = wm + mi * 16 + lm;
        float r = rws[mi];
#pragma unroll
        for (int ni = 0; ni < 4; ni++) {
            int col0 = wn + ni * 16 + q4 * 4;
            h4v o;
#pragma unroll
            for (int j = 0; j < 4; j++) o[j] = (_Float16)(acc[mi][ni][j] * r);
            *(h4v*)(qn + row * 132 + col0) = o;
        }
    }
    // stage csT[hh][e][d] = (sum_ks part[ks][bh])[d][e] * invS[d]  (f16, B^T layout)
    int bl = m0 >> 10;
    int head0 = n0 >> 6;
#pragma unroll
    for (int hh2 = 0; hh2 < 2; hh2++) {
        int bh = bl * 8 + head0 + hh2;
        const f32x4* p0 = (const f32x4*)(part + ((size_t)0 * 64 + bh) * 4096);
        const f32x4* p1 = (const f32x4*)(part + ((size_t)1 * 64 + bh) * 4096);
        const f32x4* p2 = (const f32x4*)(part + ((size_t)2 * 64 + bh) * 4096);
        const f32x4* p3 = (const f32x4*)(part + ((size_t)3 * 64 + bh) * 4096);
        for (int i = t; i < 1024; i += 256) {
            f32x4 v = p0[i] + p1[i] + p2[i] + p3[i];
            int d = i >> 4, e0 = (i & 15) * 4;
            float is = 1.f / Sbuf[bh * 64 + d];
#pragma unroll
            for (int j = 0; j < 4; j++)
                csT[hh2 * 64 * 68 + (e0 + j) * 68 + d] = (_Float16)(v[j] * is);
        }
    }
    __syncthreads();
    // PV: per wave: rows wm..+63 of its head hh = w>>1, e-cols wn&63 (== output cols)
    int hh = w >> 1;
    f32x4 acc2[4][4];
#pragma unroll
    for (int i = 0; i < 4; i++)
#pragma unroll
        for (int j = 0; j < 4; j++) acc2[i][j] = (f32x4){0.f, 0.f, 0.f, 0.f};
#pragma unroll
    for (int kc = 0; kc < 2; kc++) {
        h8 af[4], bf[4];
#pragma unroll
        for (int mi = 0; mi < 4; mi++) {
            const _Float16* p = qn + (wm + mi * 16 + lm) * 132 + hh * 64 + kc * 32 + q4 * 8;
            h4v lo = *(const h4v*)p;
            h4v hi = *(const h4v*)(p + 4);
            h8 a;
#pragma unroll
            for (int j = 0; j < 4; j++) { a[j] = lo[j]; a[4 + j] = hi[j]; }
            af[mi] = a;
        }
#pragma unroll
        for (int ni = 0; ni < 4; ni++) {
            const _Float16* p = csT + hh * 64 * 68 + (ni * 16 + lm) * 68 + kc * 32 + q4 * 8;
            h4v lo = *(const h4v*)p;
            h4v hi = *(const h4v*)(p + 4);
            h8 b;
#pragma unroll
            for (int j = 0; j < 4; j++) { b[j] = lo[j]; b[4 + j] = hi[j]; }
            bf[ni] = b;
        }
#pragma unroll
        for (int mi = 0; mi < 4; mi++)
#pragma unroll
            for (int ni = 0; ni < 4; ni++)
                acc2[mi][ni] = __builtin_amdgcn_mfma_f32_16x16x32_f16(bf[ni], af[mi], acc2[mi][ni], 0, 0, 0);
    }
#pragma unroll
    for (int mi = 0; mi < 4; mi++) {
        int row = m0 + wm + mi * 16 + lm;
#pragma unroll
        for (int ni = 0; ni < 4; ni++) {
            int col0 = n0 + wn + ni * 16 + q4 * 4;   // == h*64 + e directly
            h4v o;
#pragma unroll
            for (int r = 0; r < 4; r++) o[r] = (_Float16)acc2[mi][ni][r];
            *(h4v*)(attn + (size_t)row * 512 + col0) = o;
        }
    }
}

// ---------- fused projection GEMM + bias + LN2 + residual ----------
// out[m0+row][:] = LN( attn[row] . woutT^T / 1024 + b_out ) * ln2_scale + x[row]
// 512 threads = 8 waves (2m x 4n); tile 128 rows x 512 cols (full rows -> LN in-block).
__global__ __launch_bounds__(512) void gemm_projln2(const _Float16* __restrict__ A,
                                                    const _Float16* __restrict__ BT,
                                                    const float* __restrict__ bias,
                                                    const float* __restrict__ x,
                                                    const float* __restrict__ scale,
                                                    float* __restrict__ out) {
    __shared__ __attribute__((aligned(16))) _Float16 As[128 * 32];   //  8 KB
    __shared__ __attribute__((aligned(16))) _Float16 Bs[512 * 32];   // 32 KB
    __shared__ float rs_sum[2][64][4];                               //  2 KB
    __shared__ float rs_ssq[2][64][4];                               //  2 KB
    int t = threadIdx.x, w = t >> 6, lane = t & 63;
    int lm = lane & 15, q4 = lane >> 4;
    int m0 = blockIdx.x * 128;
    int wm = (w & 1) * 64, wn = (w >> 1) * 128;
    f32x4 acc[4][8];
#pragma unroll
    for (int i = 0; i < 4; i++)
#pragma unroll
        for (int j = 0; j < 8; j++) acc[i][j] = (f32x4){0.f, 0.f, 0.f, 0.f};

    int sr = t >> 2, sc = (t & 3) * 8;     // sr 0..127 (512 threads)
    const _Float16* Ag = A + (size_t)(m0 + sr) * 512 + sc;
    const _Float16* Bg = BT + (size_t)sr * 512 + sc;
    _Float16* AsW = As + w * 512;          // wave-uniform bases (lane*16B implied)

    for (int k0 = 0; k0 < 512; k0 += 32) {
        gload16(Ag + k0, AsW);
#pragma unroll
        for (int j = 0; j < 4; j++)
            gload16(Bg + (size_t)j * 128 * 512 + k0, Bs + j * 4096 + w * 512);
        __syncthreads();
        h8 af[4], bf[8];
#pragma unroll
        for (int i = 0; i < 4; i++) af[i] = *(const h8*)(As + (wm + i * 16 + lm) * 32 + q4 * 8);
#pragma unroll
        for (int i = 0; i < 8; i++) bf[i] = *(const h8*)(Bs + (wn + i * 16 + lm) * 32 + q4 * 8);
#pragma unroll
        for (int mi = 0; mi < 4; mi++)
#pragma unroll
            for (int ni = 0; ni < 8; ni++)
                acc[mi][ni] = __builtin_amdgcn_mfma_f32_16x16x32_f16(bf[ni], af[mi], acc[mi][ni], 0, 0, 0);
        __syncthreads();
    }
    // scale + bias in-place; per-(row,wave) partial sums over this wave's 128 cols
    const float os = 1.f / 1024.f;
    int mwi = w & 1, nwi = w >> 1;
#pragma unroll
    for (int mi = 0; mi < 4; mi++) {
        float s = 0.f, ss = 0.f;
#pragma unroll
        for (int ni = 0; ni < 8; ni++) {
            float4 b4 = *(const float4*)(bias + wn + ni * 16 + q4 * 4);
            const float* bp = &b4.x;
#pragma unroll
            for (int r = 0; r < 4; r++) {
                float v = acc[mi][ni][r] * os + bp[r];
                acc[mi][ni][r] = v;
                s += v; ss += v * v;
            }
        }
        // row's 128 cols live in the 4 lanes sharing lm (q4 = 0..3): lane bits 4,5
        s  += __shfl_xor(s, 16);  s  += __shfl_xor(s, 32);
        ss += __shfl_xor(ss, 16); ss += __shfl_xor(ss, 32);
        if (q4 == 0) {
            rs_sum[mwi][mi * 16 + lm][nwi] = s;
            rs_ssq[mwi][mi * 16 + lm][nwi] = ss;
        }
    }
    __syncthreads();
#pragma unroll
    for (int mi = 0; mi < 4; mi++) {
        int r64 = mi * 16 + lm;
        float s  = rs_sum[mwi][r64][0] + rs_sum[mwi][r64][1] + rs_sum[mwi][r64][2] + rs_sum[mwi][r64][3];
        float ss = rs_ssq[mwi][r64][0] + rs_ssq[mwi][r64][1] + rs_ssq[mwi][r64][2] + rs_ssq[mwi][r64][3];
        float mean = s * (1.f / 512.f);
        float var  = ss * (1.f / 512.f) - mean * mean;
        float rstd = rsqrtf(fmaxf(var, 0.f) + 1e-5f);
        int row = m0 + wm + r64;
#pragma unroll
        for (int ni = 0; ni < 8; ni++) {
            int col0 = wn + ni * 16 + q4 * 4;
            float4 sc4 = *(const float4*)(scale + col0);
            float4 x4  = *(const float4*)(x + (size_t)row * 512 + col0);
            const float* scp = &sc4.x; const float* xp = &x4.x;
            float4 o;
            float* op = &o.x;
#pragma unroll
            for (int r = 0; r < 4; r++)
                op[r] = (acc[mi][ni][r] - mean) * rstd * scp[r] + xp[r];
            *(float4*)(out + (size_t)row * 512 + col0) = o;
        }
    }
}

// ---------- launch ----------
extern "C" void kernel_launch(void* const* d_in, const int* in_sizes, int n_in,
                              void* d_out, int out_size, void* d_ws, size_t ws_size,
                              hipStream_t stream) {
    const float* x    = (const float*)d_in[0];
    const float* ln1s = (const float*)d_in[1];
    const float* wqkv = (const float*)d_in[2];
    const float* wout = (const float*)d_in[3];
    const float* bout = (const float*)d_in[4];
    const float* ln2s = (const float*)d_in[5];
    float* out = (float*)d_out;

    char* ws = (char*)d_ws;
    // ws (~38 MB): wqkvT | woutT | ctx_part f32 [4][64][4096] | Sbuf f32 [64][64] | normed f16
    _Float16* wqkvT  = (_Float16*)(ws);                     // 1,572,864
    _Float16* woutT  = (_Float16*)(ws + 1572864);           //   524,288
    float*    part   = (float*)(ws + 2097152);              // 4,194,304
    float*    Sbuf   = (float*)(ws + 6291456);              //    16,384
    _Float16* normed = (_Float16*)(ws + 6356992);           // 33,554,432
    // d_out (64 MiB) doubles as scratch; attnF/ekT/vT all dead before gemm_projln2 writes out.
    // (gemm_projln2 block b reads attnF rows [b*128,(b+1)*128) and writes out the same rows;
    //  out f32 rows occupy 2x the bytes of attnF f16 rows, but every block reads its full
    //  A-panel into LDS-staged MFMA state before its first out-write? NO - K-loop streams A.
    //  Safe because out rows [r] overlap attnF rows [r/2..]: block b writes bytes
    //  [b*256KB, b*256KB+256KB) of d_out and reads attnF bytes [b*128KB, b*128KB+128KB).
    //  Writes of block b land in attnF-byte-range of blocks 2b/2b+1 -> RACE for b'>b.
    //  => attnF must NOT alias d_out anymore: moved to ws (normed region is dead by then? NO,
    //  normed is read by gemm_qattn in later chunks). attnF gets its own ws slot instead.
    _Float16* attnF = (_Float16*)(ws + 39911424);                // [32768][512] f16 : 32 MiB
    _Float16* ekT   = (_Float16*)((char*)d_out + 50331648);      // chunk [64*64][1024] f16 : 8 MiB
    _Float16* vT    = (_Float16*)((char*)d_out + 58720256);      // chunk [64*64][1024] f16 : 8 MiB

    const int nb = 8, nchunks = 4;

    transpose_f2h<<<dim3(48, 16), 256, 0, stream>>>(wqkv, wqkvT, 512, 1536);
    transpose_f2h<<<dim3(16, 16), 256, 0, stream>>>(wout, woutT, 512, 512);
    ln1_kernel<<<8192, 256, 0, stream>>>(x, ln1s, normed);

    for (int c = 0; c < nchunks; c++) {
        size_t row0 = (size_t)c * nb * 1024;
        const _Float16* normed_c = normed + row0 * 512;
        hipMemsetAsync(Sbuf, 0, 16384, stream);
        // kv = normed_c . w_qkv[:, 512:1536] with fused exp/transpose/S
        gemm_kvexp<<<dim3(8, 64), 256, 0, stream>>>(normed_c, wqkvT + 512 * 512,
                                                    ekT, vT, Sbuf);
        ctx_gemm<<<dim3(64, 4), 256, 0, stream>>>(ekT, vT, part);
        // q = normed_c . w_qkv[:, 0:512] with fused softmax + PV
        gemm_qattn<<<dim3(4, 64), 256, 0, stream>>>(normed_c, wqkvT, part, Sbuf,
                                                    attnF + row0 * 512);
    }

    // out = LN(attn . w_out^T / 1024 + b_out) * ln2_scale + x   (fused, one kernel)
    gemm_projln2<<<256, 512, 0, stream>>>(attnF, woutT, bout, x, ln2s, out);
}

// Round 5
// 303.395 us; speedup vs baseline: 2.0933x; 1.2453x over previous
//
#include <hip/hip_runtime.h>
#include <stdint.h>

// ---------- types / helpers ----------
typedef _Float16 h8 __attribute__((ext_vector_type(8)));
typedef _Float16 h4v __attribute__((ext_vector_type(4)));
typedef float f32x4 __attribute__((ext_vector_type(4)));

__device__ __forceinline__ float clampf(float x, float lo, float hi) {
    return fminf(fmaxf(x, lo), hi);
}
// async global->LDS, 16B per lane; lds dest must be wave-uniform base (+ lane*16 implied)
__device__ __forceinline__ void gload16(const _Float16* g, _Float16* l) {
    __builtin_amdgcn_global_load_lds(
        (const __attribute__((address_space(1))) unsigned int*)g,
        (__attribute__((address_space(3))) unsigned int*)l, 16, 0, 0);
}

// ---------- transpose f32 -> f16 (out[c][r] = in[r][c]) ----------
__global__ __launch_bounds__(256) void transpose_f2h(const float* __restrict__ in,
                                                     _Float16* __restrict__ out,
                                                     int rows, int cols) {
    __shared__ _Float16 tile[32][33];
    int bx = blockIdx.x * 32, by = blockIdx.y * 32;
    int tx = threadIdx.x & 31, ty = threadIdx.x >> 5;
    for (int i = ty; i < 32; i += 8)
        tile[i][tx] = (_Float16)in[(size_t)(by + i) * cols + bx + tx];
    __syncthreads();
    for (int i = ty; i < 32; i += 8)
        out[(size_t)(bx + i) * rows + by + tx] = tile[tx][i];
}

// ---------- LN1: f32 x -> f16 normed (one wave per 512-ch row) ----------
__global__ __launch_bounds__(256) void ln1_kernel(const float* __restrict__ x,
                                                  const float* __restrict__ scale,
                                                  _Float16* __restrict__ out) {
    int row = blockIdx.x * 4 + (threadIdx.x >> 6);
    int lane = threadIdx.x & 63;
    const float4* xp = (const float4*)(x + (size_t)row * 512 + lane * 8);
    float4 a = xp[0], b = xp[1];
    const float4* sp = (const float4*)(scale + lane * 8);
    float4 s0v = sp[0], s1v = sp[1];
    float f[8] = {a.x, a.y, a.z, a.w, b.x, b.y, b.z, b.w};
    float sc[8] = {s0v.x, s0v.y, s0v.z, s0v.w, s1v.x, s1v.y, s1v.z, s1v.w};
    float s = 0.f, ss = 0.f;
#pragma unroll
    for (int j = 0; j < 8; j++) { s += f[j]; ss += f[j] * f[j]; }
#pragma unroll
    for (int off = 1; off < 64; off <<= 1) { s += __shfl_xor(s, off); ss += __shfl_xor(ss, off); }
    float mean = s * (1.f / 512.f);
    float var  = ss * (1.f / 512.f) - mean * mean;
    float rs   = rsqrtf(fmaxf(var, 0.f) + 1e-5f);
    union { uint4 u; _Float16 h[8]; } ov;
#pragma unroll
    for (int j = 0; j < 8; j++) ov.h[j] = (_Float16)((f[j] - mean) * rs * sc[j]);
    *(uint4*)(out + (size_t)row * 512 + lane * 8) = ov.u;
}

// ---------- fused kv GEMM (128x512 tile) + exp + transpose + S partials ----------
// A = normed [32768][512], BT = wqkvT kv-rows [1024][512].
// grid (2, 256): bx=0 -> k cols 0..511 (exp + ekT + S), bx=1 -> v cols (vT).
// 512 threads = 8 waves (2m x 4n), acc[4][8]; epilogue transposes per 128-col group.
__global__ __launch_bounds__(512) void gemm_kvexp(const _Float16* __restrict__ A,
                                                  const _Float16* __restrict__ BT,
                                                  _Float16* __restrict__ ekT,
                                                  _Float16* __restrict__ vT,
                                                  float* __restrict__ Sbuf) {
    // K-loop: As 8KB @0, Bs 32KB @8192. Epilogue: tr[128][132] f16 (33792 B) overlays.
    __shared__ __attribute__((aligned(16))) char smem[40960];
    _Float16* As = (_Float16*)smem;
    _Float16* Bs = (_Float16*)(smem + 8192);
    _Float16* tr = (_Float16*)smem;
    int t = threadIdx.x, w = t >> 6, lane = t & 63;
    int lm = lane & 15, q4 = lane >> 4;
    int m0 = blockIdx.y * 128, n0 = blockIdx.x * 512;
    int wm = (w & 1) * 64, wn = (w >> 1) * 128;
    f32x4 acc[4][8];
#pragma unroll
    for (int i = 0; i < 4; i++)
#pragma unroll
        for (int j = 0; j < 8; j++) acc[i][j] = (f32x4){0.f, 0.f, 0.f, 0.f};

    int sr = t >> 2, sc = (t & 3) * 8;     // sr 0..127
    const _Float16* Ag = A + (size_t)(m0 + sr) * 512 + sc;
    const _Float16* Bg = BT + (size_t)(n0 + sr) * 512 + sc;
    _Float16* AsW = As + w * 512;

    for (int k0 = 0; k0 < 512; k0 += 32) {
        gload16(Ag + k0, AsW);
#pragma unroll
        for (int j = 0; j < 4; j++)
            gload16(Bg + (size_t)j * 128 * 512 + k0, Bs + j * 4096 + w * 512);
        __syncthreads();
        h8 af[4], bf[8];
#pragma unroll
        for (int i = 0; i < 4; i++) af[i] = *(const h8*)(As + (wm + i * 16 + lm) * 32 + q4 * 8);
#pragma unroll
        for (int i = 0; i < 8; i++) bf[i] = *(const h8*)(Bs + (wn + i * 16 + lm) * 32 + q4 * 8);
#pragma unroll
        for (int mi = 0; mi < 4; mi++)
#pragma unroll
            for (int ni = 0; ni < 8; ni++)
                acc[mi][ni] = __builtin_amdgcn_mfma_f32_16x16x32_f16(bf[ni], af[mi], acc[mi][ni], 0, 0, 0);
        __syncthreads();
    }
    // epilogue: per 128-col group g (owned by waves w>>1==g): exp -> tr -> transposed store
    bool isK = (n0 < 512);
    int bl = m0 >> 10, nl0 = m0 & 1023;    // 1024 % 128 == 0: blocks never straddle batches
    int nw = w >> 1;
    int oc = t >> 2, qtr = t & 3;          // reader: local col 0..127, 32-n quarter
#pragma unroll
    for (int g = 0; g < 4; g++) {
        __syncthreads();                   // prior group's tr reads complete
        if (nw == g) {
#pragma unroll
            for (int mi = 0; mi < 4; mi++) {
                int row = wm + mi * 16 + lm;
#pragma unroll
                for (int ni = 0; ni < 8; ni++) {
                    int lc = ni * 16 + q4 * 4;       // col local to group
                    f32x4 v = acc[mi][ni];
#pragma unroll
                    for (int r = 0; r < 4; r++) {
                        float f = v[r];
                        if (isK) f = __expf(clampf(f, -30.f, 30.f));
                        tr[(lc + r) * 132 + row] = (_Float16)f;
                    }
                }
            }
        }
        __syncthreads();
        int c = n0 + g * 128 + oc;
        int h = (c >> 6) & 7, de = c & 63;
        _Float16* dst = (isK ? ekT : vT)
                        + ((size_t)(bl * 8 + h) * 64 + de) * 1024 + nl0 + qtr * 32;
        const _Float16* src = tr + oc * 132 + qtr * 32;
        float ssum = 0.f;
#pragma unroll
        for (int j = 0; j < 4; j++) {
            h4v u0 = *(const h4v*)(src + j * 8);
            h4v u1 = *(const h4v*)(src + j * 8 + 4);
            if (isK) {
#pragma unroll
                for (int q = 0; q < 4; q++) ssum += (float)u0[q] + (float)u1[q];
            }
            union { struct { h4v a, b; } hh; uint4 u; } uu;
            uu.hh.a = u0; uu.hh.b = u1;
            *(uint4*)(dst + j * 8) = uu.u;
        }
        if (isK) {
            ssum += __shfl_xor(ssum, 1);
            ssum += __shfl_xor(ssum, 2);   // 4 lanes share oc -> 128-n partial
            if (qtr == 0) atomicAdd(&Sbuf[(bl * 8 + h) * 64 + de], ssum);
        }
    }
}

// ---------- ctx GEMM: part[bh][d][e] = sum_n ekT[bh][d][n] * vT[bh][e][n], K=1024 ----------
// grid (256 bh); 512 threads = 8 waves: wave -> d-tile (w&3)*16, e-half (w>>2)*32.
// Threads <256 stage As (ekT), >=256 stage Bs (vT).
__global__ __launch_bounds__(512) void ctx_gemm(const _Float16* __restrict__ ekT,
                                                const _Float16* __restrict__ vT,
                                                float* __restrict__ part) {
    __shared__ __attribute__((aligned(16))) _Float16 As[64 * 32];
    __shared__ __attribute__((aligned(16))) _Float16 Bs[64 * 32];
    int t = threadIdx.x, w = t >> 6, lane = t & 63;
    int lm = lane & 15, q4 = lane >> 4;
    int bhl = blockIdx.x;
    int wd = (w & 3) * 16, we = (w >> 2) * 32;
    int tl = t & 255;
    int sr = tl >> 2, sc = (tl & 3) * 8;   // 64 rows x 32 cols per half-block
    const _Float16* G = (t >= 256 ? vT : ekT) + (size_t)bhl * 65536 + (size_t)sr * 1024 + sc;
    _Float16* LW = (t >= 256 ? Bs : As) + (w & 3) * 512;
    f32x4 acc[2];
    acc[0] = (f32x4){0.f, 0.f, 0.f, 0.f};
    acc[1] = (f32x4){0.f, 0.f, 0.f, 0.f};

    for (int k0 = 0; k0 < 1024; k0 += 32) {
        gload16(G + k0, LW);
        __syncthreads();
        h8 af = *(const h8*)(As + (wd + lm) * 32 + q4 * 8);
#pragma unroll
        for (int nt = 0; nt < 2; nt++) {
            h8 bf = *(const h8*)(Bs + (we + nt * 16 + lm) * 32 + q4 * 8);
            acc[nt] = __builtin_amdgcn_mfma_f32_16x16x32_f16(bf, af, acc[nt], 0, 0, 0);
        }
        __syncthreads();
    }
    float* dst = part + (size_t)bhl * 4096 + (wd + lm) * 64 + we;
#pragma unroll
    for (int nt = 0; nt < 2; nt++)
        *(f32x4*)(dst + nt * 16 + q4 * 4) = acc[nt];
}

// ---------- fused q GEMM + per-head softmax + PV ----------
// A = normed, BT = wqkvT q-rows. Block: 128 rows x 128 cols = 2 complete heads.
// Wave's 64 cols = one head -> softmax sum fully in-wave (shfl_xor 16,32).
// PV: attn[n][h*64+e] = sum_d qn[n][d] * csT[e][d], K=64 MFMA from LDS tiles.
__global__ __launch_bounds__(256) void gemm_qattn(const _Float16* __restrict__ A,
                                                  const _Float16* __restrict__ BT,
                                                  const float* __restrict__ part,
                                                  const float* __restrict__ Sbuf,
                                                  _Float16* __restrict__ attn) {
    // smem: As/Bs (16 KB) during K-loop; then qn[128][132] (33792 B) + csT[2][64][68] (17408 B)
    __shared__ __attribute__((aligned(16))) char smem[33792 + 17408];
    _Float16* As  = (_Float16*)smem;
    _Float16* Bs  = (_Float16*)(smem + 8192);
    _Float16* qn  = (_Float16*)smem;             // [128][132]
    _Float16* csT = (_Float16*)(smem + 33792);   // [2][64][68]
    int t = threadIdx.x, w = t >> 6, lane = t & 63;
    int lm = lane & 15, q4 = lane >> 4;
    int m0 = blockIdx.y * 128, n0 = blockIdx.x * 128;
    int wm = (w & 1) * 64, wn = (w >> 1) * 64;
    f32x4 acc[4][4];
#pragma unroll
    for (int i = 0; i < 4; i++)
#pragma unroll
        for (int j = 0; j < 4; j++) acc[i][j] = (f32x4){0.f, 0.f, 0.f, 0.f};

    int sr = t >> 2, sc = (t & 3) * 8;
    const _Float16* Ag = A + (size_t)(m0 + sr) * 512 + sc;
    const _Float16* Bg = BT + (size_t)(n0 + sr) * 512 + sc;
    _Float16* AsW = As + w * 512;
    _Float16* BsW = Bs + w * 512;

    for (int k0 = 0; k0 < 512; k0 += 32) {
        gload16(Ag + k0, AsW);
        gload16(Ag + (size_t)64 * 512 + k0, AsW + 64 * 32);
        gload16(Bg + k0, BsW);
        gload16(Bg + (size_t)64 * 512 + k0, BsW + 64 * 32);
        __syncthreads();
        h8 af[4], bf[4];
#pragma unroll
        for (int i = 0; i < 4; i++) af[i] = *(const h8*)(As + (wm + i * 16 + lm) * 32 + q4 * 8);
#pragma unroll
        for (int i = 0; i < 4; i++) bf[i] = *(const h8*)(Bs + (wn + i * 16 + lm) * 32 + q4 * 8);
#pragma unroll
        for (int mi = 0; mi < 4; mi++)
#pragma unroll
            for (int ni = 0; ni < 4; ni++)
                acc[mi][ni] = __builtin_amdgcn_mfma_f32_16x16x32_f16(bf[ni], af[mi], acc[mi][ni], 0, 0, 0);
        __syncthreads();
    }
    // per-row softmax over this wave's head (64 cols): exp in-place, row sums via shfl over q4
    float rws[4];
#pragma unroll
    for (int mi = 0; mi < 4; mi++) {
        float s = 0.f;
#pragma unroll
        for (int ni = 0; ni < 4; ni++) {
            f32x4 e;
#pragma unroll
            for (int r = 0; r < 4; r++) {
                e[r] = __expf(clampf(acc[mi][ni][r], -30.f, 30.f));
                s += e[r];
            }
            acc[mi][ni] = e;
        }
        s += __shfl_xor(s, 16);
        s += __shfl_xor(s, 32);
        rws[mi] = 1.f / (s * 8.f);           // softmax / sqrt(64)
    }
    // write qn tile (f16) to LDS (overlays As/Bs; safe after final K-loop barrier)
#pragma unroll
    for (int mi = 0; mi < 4; mi++) {
        int row = wm + mi * 16 + lm;
        float r = rws[mi];
#pragma unroll
        for (int ni = 0; ni < 4; ni++) {
            int col0 = wn + ni * 16 + q4 * 4;
            h4v o;
#pragma unroll
            for (int j = 0; j < 4; j++) o[j] = (_Float16)(acc[mi][ni][j] * r);
            *(h4v*)(qn + row * 132 + col0) = o;
        }
    }
    // stage csT[hh][e][d] = ctx[bh][d][e] * invS[d]  (f16, B^T layout)
    int bl = m0 >> 10;
    int head0 = n0 >> 6;
#pragma unroll
    for (int hh2 = 0; hh2 < 2; hh2++) {
        int bh = bl * 8 + head0 + hh2;
        const f32x4* p0 = (const f32x4*)(part + (size_t)bh * 4096);
        for (int i = t; i < 1024; i += 256) {
            f32x4 v = p0[i];
            int d = i >> 4, e0 = (i & 15) * 4;
            float is = 1.f / Sbuf[bh * 64 + d];
#pragma unroll
            for (int j = 0; j < 4; j++)
                csT[hh2 * 64 * 68 + (e0 + j) * 68 + d] = (_Float16)(v[j] * is);
        }
    }
    __syncthreads();
    // PV: per wave: rows wm..+63 of its head hh = w>>1, e-cols wn&63 (== output cols)
    int hh = w >> 1;
    f32x4 acc2[4][4];
#pragma unroll
    for (int i = 0; i < 4; i++)
#pragma unroll
        for (int j = 0; j < 4; j++) acc2[i][j] = (f32x4){0.f, 0.f, 0.f, 0.f};
#pragma unroll
    for (int kc = 0; kc < 2; kc++) {
        h8 af[4], bf[4];
#pragma unroll
        for (int mi = 0; mi < 4; mi++) {
            const _Float16* p = qn + (wm + mi * 16 + lm) * 132 + hh * 64 + kc * 32 + q4 * 8;
            h4v lo = *(const h4v*)p;
            h4v hi = *(const h4v*)(p + 4);
            h8 a;
#pragma unroll
            for (int j = 0; j < 4; j++) { a[j] = lo[j]; a[4 + j] = hi[j]; }
            af[mi] = a;
        }
#pragma unroll
        for (int ni = 0; ni < 4; ni++) {
            const _Float16* p = csT + hh * 64 * 68 + (ni * 16 + lm) * 68 + kc * 32 + q4 * 8;
            h4v lo = *(const h4v*)p;
            h4v hi = *(const h4v*)(p + 4);
            h8 b;
#pragma unroll
            for (int j = 0; j < 4; j++) { b[j] = lo[j]; b[4 + j] = hi[j]; }
            bf[ni] = b;
        }
#pragma unroll
        for (int mi = 0; mi < 4; mi++)
#pragma unroll
            for (int ni = 0; ni < 4; ni++)
                acc2[mi][ni] = __builtin_amdgcn_mfma_f32_16x16x32_f16(bf[ni], af[mi], acc2[mi][ni], 0, 0, 0);
    }
#pragma unroll
    for (int mi = 0; mi < 4; mi++) {
        int row = m0 + wm + mi * 16 + lm;
#pragma unroll
        for (int ni = 0; ni < 4; ni++) {
            int col0 = n0 + wn + ni * 16 + q4 * 4;   // == h*64 + e directly
            h4v o;
#pragma unroll
            for (int r = 0; r < 4; r++) o[r] = (_Float16)acc2[mi][ni][r];
            *(h4v*)(attn + (size_t)row * 512 + col0) = o;
        }
    }
}

// ---------- fused projection GEMM + bias + LN2 + residual ----------
// out[m0+row][:] = LN( attn[row] . woutT^T / 1024 + b_out ) * ln2_scale + x[row]
// 512 threads = 8 waves (2m x 4n); tile 128 rows x 512 cols (full rows -> LN in-block).
__global__ __launch_bounds__(512) void gemm_projln2(const _Float16* __restrict__ A,
                                                    const _Float16* __restrict__ BT,
                                                    const float* __restrict__ bias,
                                                    const float* __restrict__ x,
                                                    const float* __restrict__ scale,
                                                    float* __restrict__ out) {
    __shared__ __attribute__((aligned(16))) _Float16 As[128 * 32];   //  8 KB
    __shared__ __attribute__((aligned(16))) _Float16 Bs[512 * 32];   // 32 KB
    __shared__ float rs_sum[2][64][4];                               //  2 KB
    __shared__ float rs_ssq[2][64][4];                               //  2 KB
    int t = threadIdx.x, w = t >> 6, lane = t & 63;
    int lm = lane & 15, q4 = lane >> 4;
    int m0 = blockIdx.x * 128;
    int wm = (w & 1) * 64, wn = (w >> 1) * 128;
    f32x4 acc[4][8];
#pragma unroll
    for (int i = 0; i < 4; i++)
#pragma unroll
        for (int j = 0; j < 8; j++) acc[i][j] = (f32x4){0.f, 0.f, 0.f, 0.f};

    int sr = t >> 2, sc = (t & 3) * 8;     // sr 0..127 (512 threads)
    const _Float16* Ag = A + (size_t)(m0 + sr) * 512 + sc;
    const _Float16* Bg = BT + (size_t)sr * 512 + sc;
    _Float16* AsW = As + w * 512;          // wave-uniform bases (lane*16B implied)

    for (int k0 = 0; k0 < 512; k0 += 32) {
        gload16(Ag + k0, AsW);
#pragma unroll
        for (int j = 0; j < 4; j++)
            gload16(Bg + (size_t)j * 128 * 512 + k0, Bs + j * 4096 + w * 512);
        __syncthreads();
        h8 af[4], bf[8];
#pragma unroll
        for (int i = 0; i < 4; i++) af[i] = *(const h8*)(As + (wm + i * 16 + lm) * 32 + q4 * 8);
#pragma unroll
        for (int i = 0; i < 8; i++) bf[i] = *(const h8*)(Bs + (wn + i * 16 + lm) * 32 + q4 * 8);
#pragma unroll
        for (int mi = 0; mi < 4; mi++)
#pragma unroll
            for (int ni = 0; ni < 8; ni++)
                acc[mi][ni] = __builtin_amdgcn_mfma_f32_16x16x32_f16(bf[ni], af[mi], acc[mi][ni], 0, 0, 0);
        __syncthreads();
    }
    // scale + bias in-place; per-(row,wave) partial sums over this wave's 128 cols
    const float os = 1.f / 1024.f;
    int mwi = w & 1, nwi = w >> 1;
#pragma unroll
    for (int mi = 0; mi < 4; mi++) {
        float s = 0.f, ss = 0.f;
#pragma unroll
        for (int ni = 0; ni < 8; ni++) {
            float4 b4 = *(const float4*)(bias + wn + ni * 16 + q4 * 4);
            const float* bp = &b4.x;
#pragma unroll
            for (int r = 0; r < 4; r++) {
                float v = acc[mi][ni][r] * os + bp[r];
                acc[mi][ni][r] = v;
                s += v; ss += v * v;
            }
        }
        // row's 128 cols live in the 4 lanes sharing lm (q4 = 0..3): lane bits 4,5
        s  += __shfl_xor(s, 16);  s  += __shfl_xor(s, 32);
        ss += __shfl_xor(ss, 16); ss += __shfl_xor(ss, 32);
        if (q4 == 0) {
            rs_sum[mwi][mi * 16 + lm][nwi] = s;
            rs_ssq[mwi][mi * 16 + lm][nwi] = ss;
        }
    }
    __syncthreads();
#pragma unroll
    for (int mi = 0; mi < 4; mi++) {
        int r64 = mi * 16 + lm;
        float s  = rs_sum[mwi][r64][0] + rs_sum[mwi][r64][1] + rs_sum[mwi][r64][2] + rs_sum[mwi][r64][3];
        float ss = rs_ssq[mwi][r64][0] + rs_ssq[mwi][r64][1] + rs_ssq[mwi][r64][2] + rs_ssq[mwi][r64][3];
        float mean = s * (1.f / 512.f);
        float var  = ss * (1.f / 512.f) - mean * mean;
        float rstd = rsqrtf(fmaxf(var, 0.f) + 1e-5f);
        int row = m0 + wm + r64;
#pragma unroll
        for (int ni = 0; ni < 8; ni++) {
            int col0 = wn + ni * 16 + q4 * 4;
            float4 sc4 = *(const float4*)(scale + col0);
            float4 x4  = *(const float4*)(x + (size_t)row * 512 + col0);
            const float* scp = &sc4.x; const float* xp = &x4.x;
            float4 o;
            float* op = &o.x;
#pragma unroll
            for (int r = 0; r < 4; r++)
                op[r] = (acc[mi][ni][r] - mean) * rstd * scp[r] + xp[r];
            *(float4*)(out + (size_t)row * 512 + col0) = o;
        }
    }
}

// ---------- launch ----------
extern "C" void kernel_launch(void* const* d_in, const int* in_sizes, int n_in,
                              void* d_out, int out_size, void* d_ws, size_t ws_size,
                              hipStream_t stream) {
    const float* x    = (const float*)d_in[0];
    const float* ln1s = (const float*)d_in[1];
    const float* wqkv = (const float*)d_in[2];
    const float* wout = (const float*)d_in[3];
    const float* bout = (const float*)d_in[4];
    const float* ln2s = (const float*)d_in[5];
    float* out = (float*)d_out;

    char* ws = (char*)d_ws;
    // ws layout (73,465,856 B total — identical footprint to the previously-passing round):
    _Float16* wqkvT  = (_Float16*)(ws);                     // 1,572,864
    _Float16* woutT  = (_Float16*)(ws + 1572864);           //   524,288
    float*    part   = (float*)(ws + 2097152);              // ctx f32 [256][64][64] : 4 MiB
    float*    Sbuf   = (float*)(ws + 6291456);              // [256][64] f32 : 64 KiB
    _Float16* normed = (_Float16*)(ws + 6356992);           // [32768][512] f16 : 32 MiB
    _Float16* attnF  = (_Float16*)(ws + 39911424);          // [32768][512] f16 : 32 MiB
    // d_out (64 MiB) is scratch until gemm_projln2 (ekT/vT dead after ctx_gemm):
    _Float16* ekT = (_Float16*)d_out;                        // [256*64][1024] f16 : 32 MiB
    _Float16* vT  = (_Float16*)((char*)d_out + 33554432);    // [256*64][1024] f16 : 32 MiB

    transpose_f2h<<<dim3(48, 16), 256, 0, stream>>>(wqkv, wqkvT, 512, 1536);
    transpose_f2h<<<dim3(16, 16), 256, 0, stream>>>(wout, woutT, 512, 512);
    ln1_kernel<<<8192, 256, 0, stream>>>(x, ln1s, normed);
    hipMemsetAsync(Sbuf, 0, 65536, stream);

    // kv = normed . w_qkv[:, 512:1536] with fused exp/transpose/S (single pass, all batches)
    gemm_kvexp<<<dim3(2, 256), 512, 0, stream>>>(normed, wqkvT + 512 * 512, ekT, vT, Sbuf);
    // ctx[bh] = ekT[bh] . vT[bh]^T over full n=1024
    ctx_gemm<<<256, 512, 0, stream>>>(ekT, vT, part);
    // q = normed . w_qkv[:, 0:512] with fused softmax + PV (all batches)
    gemm_qattn<<<dim3(4, 256), 256, 0, stream>>>(normed, wqkvT, part, Sbuf, attnF);
    // out = LN(attn . w_out^T / 1024 + b_out) * ln2_scale + x
    gemm_projln2<<<256, 512, 0, stream>>>(attnF, woutT, bout, x, ln2s, out);
}

// Round 6
// 290.749 us; speedup vs baseline: 2.1844x; 1.0435x over previous
//
#include <hip/hip_runtime.h>
#include <stdint.h>

// ---------- types / helpers ----------
typedef _Float16 h8 __attribute__((ext_vector_type(8)));
typedef _Float16 h4v __attribute__((ext_vector_type(4)));
typedef float f32x4 __attribute__((ext_vector_type(4)));

__device__ __forceinline__ float clampf(float x, float lo, float hi) {
    return fminf(fmaxf(x, lo), hi);
}
// async global->LDS, 16B per lane; lds dest must be wave-uniform base (+ lane*16 implied)
__device__ __forceinline__ void gload16(const _Float16* g, _Float16* l) {
    __builtin_amdgcn_global_load_lds(
        (const __attribute__((address_space(1))) unsigned int*)g,
        (__attribute__((address_space(3))) unsigned int*)l, 16, 0, 0);
}

// ---------- transpose f32 -> f16 (out[c][r] = in[r][c]) ----------
__global__ __launch_bounds__(256) void transpose_f2h(const float* __restrict__ in,
                                                     _Float16* __restrict__ out,
                                                     int rows, int cols) {
    __shared__ _Float16 tile[32][33];
    int bx = blockIdx.x * 32, by = blockIdx.y * 32;
    int tx = threadIdx.x & 31, ty = threadIdx.x >> 5;
    for (int i = ty; i < 32; i += 8)
        tile[i][tx] = (_Float16)in[(size_t)(by + i) * cols + bx + tx];
    __syncthreads();
    for (int i = ty; i < 32; i += 8)
        out[(size_t)(bx + i) * rows + by + tx] = tile[tx][i];
}

// ---------- LN1: f32 x -> f16 normed (one wave per 512-ch row) ----------
__global__ __launch_bounds__(256) void ln1_kernel(const float* __restrict__ x,
                                                  const float* __restrict__ scale,
                                                  _Float16* __restrict__ out) {
    int row = blockIdx.x * 4 + (threadIdx.x >> 6);
    int lane = threadIdx.x & 63;
    const float4* xp = (const float4*)(x + (size_t)row * 512 + lane * 8);
    float4 a = xp[0], b = xp[1];
    const float4* sp = (const float4*)(scale + lane * 8);
    float4 s0v = sp[0], s1v = sp[1];
    float f[8] = {a.x, a.y, a.z, a.w, b.x, b.y, b.z, b.w};
    float sc[8] = {s0v.x, s0v.y, s0v.z, s0v.w, s1v.x, s1v.y, s1v.z, s1v.w};
    float s = 0.f, ss = 0.f;
#pragma unroll
    for (int j = 0; j < 8; j++) { s += f[j]; ss += f[j] * f[j]; }
#pragma unroll
    for (int off = 1; off < 64; off <<= 1) { s += __shfl_xor(s, off); ss += __shfl_xor(ss, off); }
    float mean = s * (1.f / 512.f);
    float var  = ss * (1.f / 512.f) - mean * mean;
    float rs   = rsqrtf(fmaxf(var, 0.f) + 1e-5f);
    union { uint4 u; _Float16 h[8]; } ov;
#pragma unroll
    for (int j = 0; j < 8; j++) ov.h[j] = (_Float16)((f[j] - mean) * rs * sc[j]);
    *(uint4*)(out + (size_t)row * 512 + lane * 8) = ov.u;
}

// ---------- fused kv GEMM, OUTPUT-TRANSPOSED, + exp + S partials ----------
// Computes ekT/vT[c][n] DIRECTLY: D[c][n] = sum_k W[c][k] * N[n][k] via swapped
// mfma operands (mfma(nf, wf): second operand -> rows (c), first -> cols (n)).
// Block: 128 c x 512 n, 512 threads = 8 waves (2c x 4n), acc[4][8].
// grid (64 n-blocks, 8 c-blocks): same-n-panel c-blocks spaced 64 apart -> same XCD.
// c-blocks 0..3 -> K (exp + ekT + S atomics); 4..7 -> V (vT).
__global__ __launch_bounds__(512) void gemm_kvexp(const _Float16* __restrict__ A,
                                                  const _Float16* __restrict__ BT,
                                                  _Float16* __restrict__ ekT,
                                                  _Float16* __restrict__ vT,
                                                  float* __restrict__ Sbuf) {
    __shared__ __attribute__((aligned(16))) _Float16 Ws[128 * 32];   //  8 KB (wqkvT rows = c)
    __shared__ __attribute__((aligned(16))) _Float16 Ns[512 * 32];   // 32 KB (normed rows = n)
    int t = threadIdx.x, w = t >> 6, lane = t & 63;
    int lm = lane & 15, q4 = lane >> 4;
    int n0 = blockIdx.x * 512, c0 = blockIdx.y * 128;
    int wc = (w & 1) * 64, wn = (w >> 1) * 128;
    f32x4 acc[4][8];
#pragma unroll
    for (int i = 0; i < 4; i++)
#pragma unroll
        for (int j = 0; j < 8; j++) acc[i][j] = (f32x4){0.f, 0.f, 0.f, 0.f};

    int sr = t >> 2, sc = (t & 3) * 8;     // sr 0..127
    const _Float16* Wg = BT + (size_t)(c0 + sr) * 512 + sc;
    const _Float16* Ng = A + (size_t)(n0 + sr) * 512 + sc;
    _Float16* WsW = Ws + w * 512;          // wave-uniform dests (lane*16B implied)

    for (int k0 = 0; k0 < 512; k0 += 32) {
        gload16(Wg + k0, WsW);
#pragma unroll
        for (int j = 0; j < 4; j++)
            gload16(Ng + (size_t)j * 128 * 512 + k0, Ns + j * 4096 + w * 512);
        __syncthreads();
        h8 wf[4], nf[8];
#pragma unroll
        for (int i = 0; i < 4; i++) wf[i] = *(const h8*)(Ws + (wc + i * 16 + lm) * 32 + q4 * 8);
#pragma unroll
        for (int i = 0; i < 8; i++) nf[i] = *(const h8*)(Ns + (wn + i * 16 + lm) * 32 + q4 * 8);
#pragma unroll
        for (int ci = 0; ci < 4; ci++)
#pragma unroll
            for (int nj = 0; nj < 8; nj++)
                acc[ci][nj] = __builtin_amdgcn_mfma_f32_16x16x32_f16(nf[nj], wf[ci], acc[ci][nj], 0, 0, 0);
        __syncthreads();
    }
    // epilogue: pure register -> global. Lane holds rows c = c0+wc+ci*16+lm,
    // cols n = n0+wn+nj*16+q4*4+r (4 consecutive n per acc -> h4v store).
    bool isK = (c0 < 512);
    int bl = n0 >> 10;                     // 512 | 1024: block never straddles a batch
    int nl0 = (n0 & 1023) + wn;
    _Float16* obase = isK ? ekT : vT;
#pragma unroll
    for (int ci = 0; ci < 4; ci++) {
        int c_abs = c0 + wc + ci * 16 + lm;
        int h = (c_abs >> 6) & 7, de = c_abs & 63;
        _Float16* rowp = obase + ((size_t)(bl * 8 + h) * 64 + de) * 1024 + nl0;
        float ssum = 0.f;
#pragma unroll
        for (int nj = 0; nj < 8; nj++) {
            f32x4 v = acc[ci][nj];
            h4v o;
#pragma unroll
            for (int r = 0; r < 4; r++) {
                float f = v[r];
                if (isK) f = __expf(clampf(f, -30.f, 30.f));
                _Float16 e = (_Float16)f;
                o[r] = e;
                ssum += (float)e;          // S from the f16-rounded value ctx consumes
            }
            *(h4v*)(rowp + nj * 16 + q4 * 4) = o;
        }
        if (isK) {
            ssum += __shfl_xor(ssum, 16);  // q4 group covers the wave's 128 n
            ssum += __shfl_xor(ssum, 32);
            if (q4 == 0) atomicAdd(&Sbuf[(bl * 8 + h) * 64 + de], ssum);
        }
    }
}

// ---------- ctx GEMM: part[bh][d][e] = sum_n ekT[bh][d][n] * vT[bh][e][n], K=1024 ----------
// grid (256 bh); 512 threads = 8 waves: wave -> d-tile (w&3)*16, e-half (w>>2)*32.
// Threads <256 stage As (ekT), >=256 stage Bs (vT).
__global__ __launch_bounds__(512) void ctx_gemm(const _Float16* __restrict__ ekT,
                                                const _Float16* __restrict__ vT,
                                                float* __restrict__ part) {
    __shared__ __attribute__((aligned(16))) _Float16 As[64 * 32];
    __shared__ __attribute__((aligned(16))) _Float16 Bs[64 * 32];
    int t = threadIdx.x, w = t >> 6, lane = t & 63;
    int lm = lane & 15, q4 = lane >> 4;
    int bhl = blockIdx.x;
    int wd = (w & 3) * 16, we = (w >> 2) * 32;
    int tl = t & 255;
    int sr = tl >> 2, sc = (tl & 3) * 8;   // 64 rows x 32 cols per half-block
    const _Float16* G = (t >= 256 ? vT : ekT) + (size_t)bhl * 65536 + (size_t)sr * 1024 + sc;
    _Float16* LW = (t >= 256 ? Bs : As) + (w & 3) * 512;
    f32x4 acc[2];
    acc[0] = (f32x4){0.f, 0.f, 0.f, 0.f};
    acc[1] = (f32x4){0.f, 0.f, 0.f, 0.f};

    for (int k0 = 0; k0 < 1024; k0 += 32) {
        gload16(G + k0, LW);
        __syncthreads();
        h8 af = *(const h8*)(As + (wd + lm) * 32 + q4 * 8);
#pragma unroll
        for (int nt = 0; nt < 2; nt++) {
            h8 bf = *(const h8*)(Bs + (we + nt * 16 + lm) * 32 + q4 * 8);
            acc[nt] = __builtin_amdgcn_mfma_f32_16x16x32_f16(bf, af, acc[nt], 0, 0, 0);
        }
        __syncthreads();
    }
    float* dst = part + (size_t)bhl * 4096 + (wd + lm) * 64 + we;
#pragma unroll
    for (int nt = 0; nt < 2; nt++)
        *(f32x4*)(dst + nt * 16 + q4 * 4) = acc[nt];
}

// ---------- fused q GEMM + per-head softmax + PV ----------
// A = normed, BT = wqkvT q-rows. Block: 128 rows x 128 cols = 2 complete heads.
// Wave's 64 cols = one head -> softmax sum fully in-wave (shfl_xor 16,32).
// PV: attn[n][h*64+e] = sum_d qn[n][d] * csT[e][d], K=64 MFMA from LDS tiles.
__global__ __launch_bounds__(256) void gemm_qattn(const _Float16* __restrict__ A,
                                                  const _Float16* __restrict__ BT,
                                                  const float* __restrict__ part,
                                                  const float* __restrict__ Sbuf,
                                                  _Float16* __restrict__ attn) {
    // smem: As/Bs (16 KB) during K-loop; then qn[128][132] (33792 B) + csT[2][64][68] (17408 B)
    __shared__ __attribute__((aligned(16))) char smem[33792 + 17408];
    _Float16* As  = (_Float16*)smem;
    _Float16* Bs  = (_Float16*)(smem + 8192);
    _Float16* qn  = (_Float16*)smem;             // [128][132]
    _Float16* csT = (_Float16*)(smem + 33792);   // [2][64][68]
    int t = threadIdx.x, w = t >> 6, lane = t & 63;
    int lm = lane & 15, q4 = lane >> 4;
    int m0 = blockIdx.y * 128, n0 = blockIdx.x * 128;
    int wm = (w & 1) * 64, wn = (w >> 1) * 64;
    f32x4 acc[4][4];
#pragma unroll
    for (int i = 0; i < 4; i++)
#pragma unroll
        for (int j = 0; j < 4; j++) acc[i][j] = (f32x4){0.f, 0.f, 0.f, 0.f};

    int sr = t >> 2, sc = (t & 3) * 8;
    const _Float16* Ag = A + (size_t)(m0 + sr) * 512 + sc;
    const _Float16* Bg = BT + (size_t)(n0 + sr) * 512 + sc;
    _Float16* AsW = As + w * 512;
    _Float16* BsW = Bs + w * 512;

    for (int k0 = 0; k0 < 512; k0 += 32) {
        gload16(Ag + k0, AsW);
        gload16(Ag + (size_t)64 * 512 + k0, AsW + 64 * 32);
        gload16(Bg + k0, BsW);
        gload16(Bg + (size_t)64 * 512 + k0, BsW + 64 * 32);
        __syncthreads();
        h8 af[4], bf[4];
#pragma unroll
        for (int i = 0; i < 4; i++) af[i] = *(const h8*)(As + (wm + i * 16 + lm) * 32 + q4 * 8);
#pragma unroll
        for (int i = 0; i < 4; i++) bf[i] = *(const h8*)(Bs + (wn + i * 16 + lm) * 32 + q4 * 8);
#pragma unroll
        for (int mi = 0; mi < 4; mi++)
#pragma unroll
            for (int ni = 0; ni < 4; ni++)
                acc[mi][ni] = __builtin_amdgcn_mfma_f32_16x16x32_f16(bf[ni], af[mi], acc[mi][ni], 0, 0, 0);
        __syncthreads();
    }
    // per-row softmax over this wave's head (64 cols): exp in-place, row sums via shfl over q4
    float rws[4];
#pragma unroll
    for (int mi = 0; mi < 4; mi++) {
        float s = 0.f;
#pragma unroll
        for (int ni = 0; ni < 4; ni++) {
            f32x4 e;
#pragma unroll
            for (int r = 0; r < 4; r++) {
                e[r] = __expf(clampf(acc[mi][ni][r], -30.f, 30.f));
                s += e[r];
            }
            acc[mi][ni] = e;
        }
        s += __shfl_xor(s, 16);
        s += __shfl_xor(s, 32);
        rws[mi] = 1.f / (s * 8.f);           // softmax / sqrt(64)
    }
    // write qn tile (f16) to LDS (overlays As/Bs; safe after final K-loop barrier)
#pragma unroll
    for (int mi = 0; mi < 4; mi++) {
        int row = wm + mi * 16 + lm;
        float r = rws[mi];
#pragma unroll
        for (int ni = 0; ni < 4; ni++) {
            int col0 = wn + ni * 16 + q4 * 4;
            h4v o;
#pragma unroll
            for (int j = 0; j < 4; j++) o[j] = (_Float16)(acc[mi][ni][j] * r);
            *(h4v*)(qn + row * 132 + col0) = o;
        }
    }
    // stage csT[hh][e][d] = ctx[bh][d][e] * invS[d]  (f16, B^T layout)
    int bl = m0 >> 10;
    int head0 = n0 >> 6;
#pragma unroll
    for (int hh2 = 0; hh2 < 2; hh2++) {
        int bh = bl * 8 + head0 + hh2;
        const f32x4* p0 = (const f32x4*)(part + (size_t)bh * 4096);
        for (int i = t; i < 1024; i += 256) {
            f32x4 v = p0[i];
            int d = i >> 4, e0 = (i & 15) * 4;
            float is = 1.f / Sbuf[bh * 64 + d];
#pragma unroll
            for (int j = 0; j < 4; j++)
                csT[hh2 * 64 * 68 + (e0 + j) * 68 + d] = (_Float16)(v[j] * is);
        }
    }
    __syncthreads();
    // PV: per wave: rows wm..+63 of its head hh = w>>1, e-cols wn&63 (== output cols)
    int hh = w >> 1;
    f32x4 acc2[4][4];
#pragma unroll
    for (int i = 0; i < 4; i++)
#pragma unroll
        for (int j = 0; j < 4; j++) acc2[i][j] = (f32x4){0.f, 0.f, 0.f, 0.f};
#pragma unroll
    for (int kc = 0; kc < 2; kc++) {
        h8 af[4], bf[4];
#pragma unroll
        for (int mi = 0; mi < 4; mi++) {
            const _Float16* p = qn + (wm + mi * 16 + lm) * 132 + hh * 64 + kc * 32 + q4 * 8;
            h4v lo = *(const h4v*)p;
            h4v hi = *(const h4v*)(p + 4);
            h8 a;
#pragma unroll
            for (int j = 0; j < 4; j++) { a[j] = lo[j]; a[4 + j] = hi[j]; }
            af[mi] = a;
        }
#pragma unroll
        for (int ni = 0; ni < 4; ni++) {
            const _Float16* p = csT + hh * 64 * 68 + (ni * 16 + lm) * 68 + kc * 32 + q4 * 8;
            h4v lo = *(const h4v*)p;
            h4v hi = *(const h4v*)(p + 4);
            h8 b;
#pragma unroll
            for (int j = 0; j < 4; j++) { b[j] = lo[j]; b[4 + j] = hi[j]; }
            bf[ni] = b;
        }
#pragma unroll
        for (int mi = 0; mi < 4; mi++)
#pragma unroll
            for (int ni = 0; ni < 4; ni++)
                acc2[mi][ni] = __builtin_amdgcn_mfma_f32_16x16x32_f16(bf[ni], af[mi], acc2[mi][ni], 0, 0, 0);
    }
#pragma unroll
    for (int mi = 0; mi < 4; mi++) {
        int row = m0 + wm + mi * 16 + lm;
#pragma unroll
        for (int ni = 0; ni < 4; ni++) {
            int col0 = n0 + wn + ni * 16 + q4 * 4;   // == h*64 + e directly
            h4v o;
#pragma unroll
            for (int r = 0; r < 4; r++) o[r] = (_Float16)acc2[mi][ni][r];
            *(h4v*)(attn + (size_t)row * 512 + col0) = o;
        }
    }
}

// ---------- fused projection GEMM + bias + LN2 + residual ----------
// out[m0+row][:] = LN( attn[row] . woutT^T / 1024 + b_out ) * ln2_scale + x[row]
// 512 threads = 8 waves (2m x 4n); tile 128 rows x 512 cols (full rows -> LN in-block).
__global__ __launch_bounds__(512) void gemm_projln2(const _Float16* __restrict__ A,
                                                    const _Float16* __restrict__ BT,
                                                    const float* __restrict__ bias,
                                                    const float* __restrict__ x,
                                                    const float* __restrict__ scale,
                                                    float* __restrict__ out) {
    __shared__ __attribute__((aligned(16))) _Float16 As[128 * 32];   //  8 KB
    __shared__ __attribute__((aligned(16))) _Float16 Bs[512 * 32];   // 32 KB
    __shared__ float rs_sum[2][64][4];                               //  2 KB
    __shared__ float rs_ssq[2][64][4];                               //  2 KB
    int t = threadIdx.x, w = t >> 6, lane = t & 63;
    int lm = lane & 15, q4 = lane >> 4;
    int m0 = blockIdx.x * 128;
    int wm = (w & 1) * 64, wn = (w >> 1) * 128;
    f32x4 acc[4][8];
#pragma unroll
    for (int i = 0; i < 4; i++)
#pragma unroll
        for (int j = 0; j < 8; j++) acc[i][j] = (f32x4){0.f, 0.f, 0.f, 0.f};

    int sr = t >> 2, sc = (t & 3) * 8;     // sr 0..127 (512 threads)
    const _Float16* Ag = A + (size_t)(m0 + sr) * 512 + sc;
    const _Float16* Bg = BT + (size_t)sr * 512 + sc;
    _Float16* AsW = As + w * 512;          // wave-uniform bases (lane*16B implied)

    for (int k0 = 0; k0 < 512; k0 += 32) {
        gload16(Ag + k0, AsW);
#pragma unroll
        for (int j = 0; j < 4; j++)
            gload16(Bg + (size_t)j * 128 * 512 + k0, Bs + j * 4096 + w * 512);
        __syncthreads();
        h8 af[4], bf[8];
#pragma unroll
        for (int i = 0; i < 4; i++) af[i] = *(const h8*)(As + (wm + i * 16 + lm) * 32 + q4 * 8);
#pragma unroll
        for (int i = 0; i < 8; i++) bf[i] = *(const h8*)(Bs + (wn + i * 16 + lm) * 32 + q4 * 8);
#pragma unroll
        for (int mi = 0; mi < 4; mi++)
#pragma unroll
            for (int ni = 0; ni < 8; ni++)
                acc[mi][ni] = __builtin_amdgcn_mfma_f32_16x16x32_f16(bf[ni], af[mi], acc[mi][ni], 0, 0, 0);
        __syncthreads();
    }
    // scale + bias in-place; per-(row,wave) partial sums over this wave's 128 cols
    const float os = 1.f / 1024.f;
    int mwi = w & 1, nwi = w >> 1;
#pragma unroll
    for (int mi = 0; mi < 4; mi++) {
        float s = 0.f, ss = 0.f;
#pragma unroll
        for (int ni = 0; ni < 8; ni++) {
            float4 b4 = *(const float4*)(bias + wn + ni * 16 + q4 * 4);
            const float* bp = &b4.x;
#pragma unroll
            for (int r = 0; r < 4; r++) {
                float v = acc[mi][ni][r] * os + bp[r];
                acc[mi][ni][r] = v;
                s += v; ss += v * v;
            }
        }
        // row's 128 cols live in the 4 lanes sharing lm (q4 = 0..3): lane bits 4,5
        s  += __shfl_xor(s, 16);  s  += __shfl_xor(s, 32);
        ss += __shfl_xor(ss, 16); ss += __shfl_xor(ss, 32);
        if (q4 == 0) {
            rs_sum[mwi][mi * 16 + lm][nwi] = s;
            rs_ssq[mwi][mi * 16 + lm][nwi] = ss;
        }
    }
    __syncthreads();
#pragma unroll
    for (int mi = 0; mi < 4; mi++) {
        int r64 = mi * 16 + lm;
        float s  = rs_sum[mwi][r64][0] + rs_sum[mwi][r64][1] + rs_sum[mwi][r64][2] + rs_sum[mwi][r64][3];
        float ss = rs_ssq[mwi][r64][0] + rs_ssq[mwi][r64][1] + rs_ssq[mwi][r64][2] + rs_ssq[mwi][r64][3];
        float mean = s * (1.f / 512.f);
        float var  = ss * (1.f / 512.f) - mean * mean;
        float rstd = rsqrtf(fmaxf(var, 0.f) + 1e-5f);
        int row = m0 + wm + r64;
#pragma unroll
        for (int ni = 0; ni < 8; ni++) {
            int col0 = wn + ni * 16 + q4 * 4;
            float4 sc4 = *(const float4*)(scale + col0);
            float4 x4  = *(const float4*)(x + (size_t)row * 512 + col0);
            const float* scp = &sc4.x; const float* xp = &x4.x;
            float4 o;
            float* op = &o.x;
#pragma unroll
            for (int r = 0; r < 4; r++)
                op[r] = (acc[mi][ni][r] - mean) * rstd * scp[r] + xp[r];
            *(float4*)(out + (size_t)row * 512 + col0) = o;
        }
    }
}

// ---------- launch ----------
extern "C" void kernel_launch(void* const* d_in, const int* in_sizes, int n_in,
                              void* d_out, int out_size, void* d_ws, size_t ws_size,
                              hipStream_t stream) {
    const float* x    = (const float*)d_in[0];
    const float* ln1s = (const float*)d_in[1];
    const float* wqkv = (const float*)d_in[2];
    const float* wout = (const float*)d_in[3];
    const float* bout = (const float*)d_in[4];
    const float* ln2s = (const float*)d_in[5];
    float* out = (float*)d_out;

    char* ws = (char*)d_ws;
    // ws layout (73,465,856 B total — identical footprint to the previously-passing round):
    _Float16* wqkvT  = (_Float16*)(ws);                     // 1,572,864
    _Float16* woutT  = (_Float16*)(ws + 1572864);           //   524,288
    float*    part   = (float*)(ws + 2097152);              // ctx f32 [256][64][64] : 4 MiB
    float*    Sbuf   = (float*)(ws + 6291456);              // [256][64] f32 : 64 KiB
    _Float16* normed = (_Float16*)(ws + 6356992);           // [32768][512] f16 : 32 MiB
    _Float16* attnF  = (_Float16*)(ws + 39911424);          // [32768][512] f16 : 32 MiB
    // d_out (64 MiB) is scratch until gemm_projln2 (ekT/vT dead after ctx_gemm):
    _Float16* ekT = (_Float16*)d_out;                        // [256*64][1024] f16 : 32 MiB
    _Float16* vT  = (_Float16*)((char*)d_out + 33554432);    // [256*64][1024] f16 : 32 MiB

    transpose_f2h<<<dim3(48, 16), 256, 0, stream>>>(wqkv, wqkvT, 512, 1536);
    transpose_f2h<<<dim3(16, 16), 256, 0, stream>>>(wout, woutT, 512, 512);
    ln1_kernel<<<8192, 256, 0, stream>>>(x, ln1s, normed);
    hipMemsetAsync(Sbuf, 0, 65536, stream);

    // kv = normed . w_qkv[:, 512:1536], output-transposed directly to ekT/vT (+exp, +S)
    gemm_kvexp<<<dim3(64, 8), 512, 0, stream>>>(normed, wqkvT + 512 * 512, ekT, vT, Sbuf);
    // ctx[bh] = ekT[bh] . vT[bh]^T over full n=1024
    ctx_gemm<<<256, 512, 0, stream>>>(ekT, vT, part);
    // q = normed . w_qkv[:, 0:512] with fused softmax + PV (all batches)
    gemm_qattn<<<dim3(4, 256), 256, 0, stream>>>(normed, wqkvT, part, Sbuf, attnF);
    // out = LN(attn . w_out^T / 1024 + b_out) * ln2_scale + x
    gemm_projln2<<<256, 512, 0, stream>>>(attnF, woutT, bout, x, ln2s, out);
}

// Round 8
// 274.920 us; speedup vs baseline: 2.3101x; 1.0576x over previous
//
#include <hip/hip_runtime.h>
#include <stdint.h>

// ---------- types / helpers ----------
typedef _Float16 h8 __attribute__((ext_vector_type(8)));
typedef _Float16 h4v __attribute__((ext_vector_type(4)));
typedef float f32x4 __attribute__((ext_vector_type(4)));

__device__ __forceinline__ float clampf(float x, float lo, float hi) {
    return fminf(fmaxf(x, lo), hi);
}
// async global->LDS, 16B per lane; lds dest must be wave-uniform base (+ lane*16 implied)
__device__ __forceinline__ void gload16(const _Float16* g, _Float16* l) {
    __builtin_amdgcn_global_load_lds(
        (const __attribute__((address_space(1))) unsigned int*)g,
        (__attribute__((address_space(3))) unsigned int*)l, 16, 0, 0);
}

// ---------- transpose f32 -> f16 (out[c][r] = in[r][c]) ----------
__global__ __launch_bounds__(256) void transpose_f2h(const float* __restrict__ in,
                                                     _Float16* __restrict__ out,
                                                     int rows, int cols) {
    __shared__ _Float16 tile[32][33];
    int bx = blockIdx.x * 32, by = blockIdx.y * 32;
    int tx = threadIdx.x & 31, ty = threadIdx.x >> 5;
    for (int i = ty; i < 32; i += 8)
        tile[i][tx] = (_Float16)in[(size_t)(by + i) * cols + bx + tx];
    __syncthreads();
    for (int i = ty; i < 32; i += 8)
        out[(size_t)(bx + i) * rows + by + tx] = tile[tx][i];
}

// ---------- LN1: f32 x -> f16 normed (one wave per 512-ch row) ----------
__global__ __launch_bounds__(256) void ln1_kernel(const float* __restrict__ x,
                                                  const float* __restrict__ scale,
                                                  _Float16* __restrict__ out) {
    int row = blockIdx.x * 4 + (threadIdx.x >> 6);
    int lane = threadIdx.x & 63;
    const float4* xp = (const float4*)(x + (size_t)row * 512 + lane * 8);
    float4 a = xp[0], b = xp[1];
    const float4* sp = (const float4*)(scale + lane * 8);
    float4 s0v = sp[0], s1v = sp[1];
    float f[8] = {a.x, a.y, a.z, a.w, b.x, b.y, b.z, b.w};
    float sc[8] = {s0v.x, s0v.y, s0v.z, s0v.w, s1v.x, s1v.y, s1v.z, s1v.w};
    float s = 0.f, ss = 0.f;
#pragma unroll
    for (int j = 0; j < 8; j++) { s += f[j]; ss += f[j] * f[j]; }
#pragma unroll
    for (int off = 1; off < 64; off <<= 1) { s += __shfl_xor(s, off); ss += __shfl_xor(ss, off); }
    float mean = s * (1.f / 512.f);
    float var  = ss * (1.f / 512.f) - mean * mean;
    float rs   = rsqrtf(fmaxf(var, 0.f) + 1e-5f);
    union { uint4 u; _Float16 h[8]; } ov;
#pragma unroll
    for (int j = 0; j < 8; j++) ov.h[j] = (_Float16)((f[j] - mean) * rs * sc[j]);
    *(uint4*)(out + (size_t)row * 512 + lane * 8) = ov.u;
}

// ---------- fused kv GEMM + exp + S + ctx (no kv materialization) ----------
// Block = one (batch bl, head h, n-half ns): 512 n-rows x 128 c (64 k-rows + 64 v-rows
// of the kv half of wqkvT). Swapped mfma -> acc = D[c][n] in registers.
// Epilogue: k-waves exp in-reg; 4 n-chunk phases {owner pair writes T[128][136] in LDS;
// all waves accumulate ctx partial via MFMA over K=128}; S from f16-rounded values.
// part2[ns][bh][d][e] f32 (summed by qattn).
__global__ __launch_bounds__(512) void gemm_kvctx(const _Float16* __restrict__ A,
                                                  const _Float16* __restrict__ BT,   // kv half
                                                  float* __restrict__ part2,
                                                  float* __restrict__ Sbuf) {
    __shared__ __attribute__((aligned(16))) char smem[40960];
    _Float16* Ws = (_Float16*)smem;            // [128][32]  8 KB (rows 0..63 k, 64..127 v)
    _Float16* Ns = (_Float16*)(smem + 8192);   // [512][32] 32 KB
    _Float16* T  = (_Float16*)smem;            // [128][136] overlay, 34816 B (16B-aligned rows)
    int t = threadIdx.x, w = t >> 6, lane = t & 63;
    int lm = lane & 15, q4 = lane >> 4;
    int ns = blockIdx.x, bh = blockIdx.y;
    int bl = bh >> 3, h = bh & 7;
    int nr0 = bl * 1024 + ns * 512;
    int wc = (w & 1) * 64, wn = (w >> 1) * 128;
    f32x4 acc[4][8];                           // [ci][nj]: c = wc+ci*16+lm, n = wn+nj*16+q4*4+r
#pragma unroll
    for (int i = 0; i < 4; i++)
#pragma unroll
        for (int j = 0; j < 8; j++) acc[i][j] = (f32x4){0.f, 0.f, 0.f, 0.f};

    int sr = t >> 2, sc = (t & 3) * 8;         // sr 0..127
    int grow = (sr < 64) ? (h * 64 + sr) : (512 + h * 64 + (sr - 64));
    const _Float16* Wg = BT + (size_t)grow * 512 + sc;
    const _Float16* Ng = A + (size_t)(nr0 + sr) * 512 + sc;
    _Float16* WsW = Ws + w * 512;              // wave-uniform dests (lane*16B implied)

    for (int k0 = 0; k0 < 512; k0 += 32) {
        gload16(Wg + k0, WsW);
#pragma unroll
        for (int j = 0; j < 4; j++)
            gload16(Ng + (size_t)j * 128 * 512 + k0, Ns + j * 4096 + w * 512);
        __syncthreads();
        h8 wf[4], nf[8];
#pragma unroll
        for (int i = 0; i < 4; i++) wf[i] = *(const h8*)(Ws + (wc + i * 16 + lm) * 32 + q4 * 8);
#pragma unroll
        for (int i = 0; i < 8; i++) nf[i] = *(const h8*)(Ns + (wn + i * 16 + lm) * 32 + q4 * 8);
#pragma unroll
        for (int ci = 0; ci < 4; ci++)
#pragma unroll
            for (int nj = 0; nj < 8; nj++)
                acc[ci][nj] = __builtin_amdgcn_mfma_f32_16x16x32_f16(nf[nj], wf[ci], acc[ci][nj], 0, 0, 0);
        __syncthreads();
    }
    // pre-pass: k-waves exponentiate in registers (parallel, no barrier needed)
    if ((w & 1) == 0) {
#pragma unroll
        for (int ci = 0; ci < 4; ci++)
#pragma unroll
            for (int nj = 0; nj < 8; nj++) {
                f32x4 v = acc[ci][nj];
#pragma unroll
                for (int r = 0; r < 4; r++) v[r] = __expf(clampf(v[r], -30.f, 30.f));
                acc[ci][nj] = v;
            }
    }
    int myChunk = w >> 1;                      // n-chunk this wave holds (0..3)
    int wd = (w & 3) * 16, we = (w >> 2) * 32; // ctx roles: d-tile, e-half
    f32x4 acc2[2];
    acc2[0] = (f32x4){0.f, 0.f, 0.f, 0.f};
    acc2[1] = (f32x4){0.f, 0.f, 0.f, 0.f};
    float ssum[4] = {0.f, 0.f, 0.f, 0.f};

#pragma unroll
    for (int j = 0; j < 4; j++) {
        if (myChunk == j) {                    // wave pair 2j (k), 2j+1 (v) writes T
            int rbase = (w & 1) * 64;
#pragma unroll
            for (int ci = 0; ci < 4; ci++) {
                float ss = 0.f;
#pragma unroll
                for (int nj = 0; nj < 8; nj++) {
                    f32x4 v = acc[ci][nj];
                    h4v o;
#pragma unroll
                    for (int r = 0; r < 4; r++) {
                        _Float16 e = (_Float16)v[r];
                        o[r] = e;
                        ss += (float)e;        // f16-rounded value ctx consumes
                    }
                    *(h4v*)(T + (rbase + ci * 16 + lm) * 136 + nj * 16 + q4 * 4) = o;
                }
                ssum[ci] = ss;                 // only meaningful for k-waves
            }
        }
        __syncthreads();                       // T chunk ready
#pragma unroll
        for (int ks = 0; ks < 4; ks++) {
            h8 af = *(const h8*)(T + (wd + lm) * 136 + ks * 32 + q4 * 8);
#pragma unroll
            for (int nt = 0; nt < 2; nt++) {
                h8 bf = *(const h8*)(T + (64 + we + nt * 16 + lm) * 136 + ks * 32 + q4 * 8);
                acc2[nt] = __builtin_amdgcn_mfma_f32_16x16x32_f16(bf, af, acc2[nt], 0, 0, 0);
            }
        }
        __syncthreads();                       // all ctx reads done before next chunk write
    }
    // S atomics: k-waves, d = ci*16+lm; q4 group covers the wave's 128 n
    if ((w & 1) == 0) {
#pragma unroll
        for (int ci = 0; ci < 4; ci++) {
            float s2 = ssum[ci];
            s2 += __shfl_xor(s2, 16);
            s2 += __shfl_xor(s2, 32);
            if (q4 == 0) atomicAdd(&Sbuf[bh * 64 + ci * 16 + lm], s2);
        }
    }
    float* dst = part2 + ((size_t)ns * 256 + bh) * 4096 + (wd + lm) * 64 + we;
#pragma unroll
    for (int nt = 0; nt < 2; nt++)
        *(f32x4*)(dst + nt * 16 + q4 * 4) = acc2[nt];
}

// ---------- fused q GEMM + per-head softmax + PV ----------
// A = normed, BT = wqkvT q-rows. Block: 128 rows x 128 cols = 2 complete heads.
// Wave's 64 cols = one head -> softmax sum fully in-wave (shfl_xor 16,32).
// PV: attn[n][h*64+e] = sum_d qn[n][d] * csT[e][d], K=64 MFMA from LDS tiles.
__global__ __launch_bounds__(256) void gemm_qattn(const _Float16* __restrict__ A,
                                                  const _Float16* __restrict__ BT,
                                                  const float* __restrict__ part,
                                                  const float* __restrict__ Sbuf,
                                                  _Float16* __restrict__ attn) {
    // smem: As/Bs (16 KB) during K-loop; then qn[128][132] (33792 B) + csT[2][64][68] (17408 B)
    __shared__ __attribute__((aligned(16))) char smem[33792 + 17408];
    _Float16* As  = (_Float16*)smem;
    _Float16* Bs  = (_Float16*)(smem + 8192);
    _Float16* qn  = (_Float16*)smem;             // [128][132]
    _Float16* csT = (_Float16*)(smem + 33792);   // [2][64][68]
    int t = threadIdx.x, w = t >> 6, lane = t & 63;
    int lm = lane & 15, q4 = lane >> 4;
    int m0 = blockIdx.y * 128, n0 = blockIdx.x * 128;
    int wm = (w & 1) * 64, wn = (w >> 1) * 64;
    f32x4 acc[4][4];
#pragma unroll
    for (int i = 0; i < 4; i++)
#pragma unroll
        for (int j = 0; j < 4; j++) acc[i][j] = (f32x4){0.f, 0.f, 0.f, 0.f};

    int sr = t >> 2, sc = (t & 3) * 8;
    const _Float16* Ag = A + (size_t)(m0 + sr) * 512 + sc;
    const _Float16* Bg = BT + (size_t)(n0 + sr) * 512 + sc;
    _Float16* AsW = As + w * 512;
    _Float16* BsW = Bs + w * 512;

    for (int k0 = 0; k0 < 512; k0 += 32) {
        gload16(Ag + k0, AsW);
        gload16(Ag + (size_t)64 * 512 + k0, AsW + 64 * 32);
        gload16(Bg + k0, BsW);
        gload16(Bg + (size_t)64 * 512 + k0, BsW + 64 * 32);
        __syncthreads();
        h8 af[4], bf[4];
#pragma unroll
        for (int i = 0; i < 4; i++) af[i] = *(const h8*)(As + (wm + i * 16 + lm) * 32 + q4 * 8);
#pragma unroll
        for (int i = 0; i < 4; i++) bf[i] = *(const h8*)(Bs + (wn + i * 16 + lm) * 32 + q4 * 8);
#pragma unroll
        for (int mi = 0; mi < 4; mi++)
#pragma unroll
            for (int ni = 0; ni < 4; ni++)
                acc[mi][ni] = __builtin_amdgcn_mfma_f32_16x16x32_f16(bf[ni], af[mi], acc[mi][ni], 0, 0, 0);
        __syncthreads();
    }
    // per-row softmax over this wave's head (64 cols): exp in-place, row sums via shfl over q4
    float rws[4];
#pragma unroll
    for (int mi = 0; mi < 4; mi++) {
        float s = 0.f;
#pragma unroll
        for (int ni = 0; ni < 4; ni++) {
            f32x4 e;
#pragma unroll
            for (int r = 0; r < 4; r++) {
                e[r] = __expf(clampf(acc[mi][ni][r], -30.f, 30.f));
                s += e[r];
            }
            acc[mi][ni] = e;
        }
        s += __shfl_xor(s, 16);
        s += __shfl_xor(s, 32);
        rws[mi] = 1.f / (s * 8.f);           // softmax / sqrt(64)
    }
    // write qn tile (f16) to LDS (overlays As/Bs; safe after final K-loop barrier)
#pragma unroll
    for (int mi = 0; mi < 4; mi++) {
        int row = wm + mi * 16 + lm;
        float r = rws[mi];
#pragma unroll
        for (int ni = 0; ni < 4; ni++) {
            int col0 = wn + ni * 16 + q4 * 4;
            h4v o;
#pragma unroll
            for (int j = 0; j < 4; j++) o[j] = (_Float16)(acc[mi][ni][j] * r);
            *(h4v*)(qn + row * 132 + col0) = o;
        }
    }
    // stage csT[hh][e][d] = (part2[0]+part2[1])[bh][d][e] * invS[d]  (f16, B^T layout)
    int bl = m0 >> 10;
    int head0 = n0 >> 6;
#pragma unroll
    for (int hh2 = 0; hh2 < 2; hh2++) {
        int bh = bl * 8 + head0 + hh2;
        const f32x4* p0 = (const f32x4*)(part + (size_t)bh * 4096);
        const f32x4* p1 = (const f32x4*)(part + (size_t)(256 + bh) * 4096);
        for (int i = t; i < 1024; i += 256) {
            f32x4 v = p0[i] + p1[i];
            int d = i >> 4, e0 = (i & 15) * 4;
            float is = 1.f / Sbuf[bh * 64 + d];
#pragma unroll
            for (int j = 0; j < 4; j++)
                csT[hh2 * 64 * 68 + (e0 + j) * 68 + d] = (_Float16)(v[j] * is);
        }
    }
    __syncthreads();
    // PV: per wave: rows wm..+63 of its head hh = w>>1, e-cols wn&63 (== output cols)
    int hh = w >> 1;
    f32x4 acc2[4][4];
#pragma unroll
    for (int i = 0; i < 4; i++)
#pragma unroll
        for (int j = 0; j < 4; j++) acc2[i][j] = (f32x4){0.f, 0.f, 0.f, 0.f};
#pragma unroll
    for (int kc = 0; kc < 2; kc++) {
        h8 af[4], bf[4];
#pragma unroll
        for (int mi = 0; mi < 4; mi++) {
            const _Float16* p = qn + (wm + mi * 16 + lm) * 132 + hh * 64 + kc * 32 + q4 * 8;
            h4v lo = *(const h4v*)p;
            h4v hi = *(const h4v*)(p + 4);
            h8 a;
#pragma unroll
            for (int j = 0; j < 4; j++) { a[j] = lo[j]; a[4 + j] = hi[j]; }
            af[mi] = a;
        }
#pragma unroll
        for (int ni = 0; ni < 4; ni++) {
            const _Float16* p = csT + hh * 64 * 68 + (ni * 16 + lm) * 68 + kc * 32 + q4 * 8;
            h4v lo = *(const h4v*)p;
            h4v hi = *(const h4v*)(p + 4);
            h8 b;
#pragma unroll
            for (int j = 0; j < 4; j++) { b[j] = lo[j]; b[4 + j] = hi[j]; }
            bf[ni] = b;
        }
#pragma unroll
        for (int mi = 0; mi < 4; mi++)
#pragma unroll
            for (int ni = 0; ni < 4; ni++)
                acc2[mi][ni] = __builtin_amdgcn_mfma_f32_16x16x32_f16(bf[ni], af[mi], acc2[mi][ni], 0, 0, 0);
    }
#pragma unroll
    for (int mi = 0; mi < 4; mi++) {
        int row = m0 + wm + mi * 16 + lm;
#pragma unroll
        for (int ni = 0; ni < 4; ni++) {
            int col0 = n0 + wn + ni * 16 + q4 * 4;   // == h*64 + e directly
            h4v o;
#pragma unroll
            for (int r = 0; r < 4; r++) o[r] = (_Float16)acc2[mi][ni][r];
            *(h4v*)(attn + (size_t)row * 512 + col0) = o;
        }
    }
}

// ---------- fused projection GEMM + bias + LN2 + residual (64-row blocks) ----------
// out[m0+row][:] = LN( attn[row] . woutT^T / 1024 + b_out ) * ln2_scale + x[row]
// 512 threads = 8 waves, each wave -> 64-col slice; 64 rows/block (full rows -> LN in-block).
__global__ __launch_bounds__(512) void gemm_projln2(const _Float16* __restrict__ A,
                                                    const _Float16* __restrict__ BT,
                                                    const float* __restrict__ bias,
                                                    const float* __restrict__ x,
                                                    const float* __restrict__ scale,
                                                    float* __restrict__ out) {
    __shared__ __attribute__((aligned(16))) _Float16 As[64 * 32];    //  4 KB
    __shared__ __attribute__((aligned(16))) _Float16 Bs[512 * 32];   // 32 KB
    __shared__ float rs_sum[64][8];                                  //  2 KB
    __shared__ float rs_ssq[64][8];                                  //  2 KB
    int t = threadIdx.x, w = t >> 6, lane = t & 63;
    int lm = lane & 15, q4 = lane >> 4;
    int m0 = blockIdx.x * 64;
    f32x4 acc[4][4];   // [mi][ni]: row = m0+mi*16+lm, col = w*64+ni*16+q4*4+r
#pragma unroll
    for (int i = 0; i < 4; i++)
#pragma unroll
        for (int j = 0; j < 4; j++) acc[i][j] = (f32x4){0.f, 0.f, 0.f, 0.f};

    int sr = t >> 2, sc = (t & 3) * 8;     // B staging: rows 0..127 per call
    const _Float16* Ag = A + (size_t)(m0 + (w & 3) * 16 + (lane >> 2)) * 512 + (lane & 3) * 8;
    const _Float16* Bg = BT + (size_t)sr * 512 + sc;
    _Float16* AsW = As + (w & 3) * 512;    // wave-uniform (lane*16B implied)

    for (int k0 = 0; k0 < 512; k0 += 32) {
        if (w < 4) gload16(Ag + k0, AsW);  // waves 0-3 stage 16 rows each
#pragma unroll
        for (int j = 0; j < 4; j++)
            gload16(Bg + (size_t)j * 128 * 512 + k0, Bs + j * 4096 + w * 512);
        __syncthreads();
        h8 af[4], bf[4];
#pragma unroll
        for (int i = 0; i < 4; i++) af[i] = *(const h8*)(As + (i * 16 + lm) * 32 + q4 * 8);
#pragma unroll
        for (int i = 0; i < 4; i++) bf[i] = *(const h8*)(Bs + (w * 64 + i * 16 + lm) * 32 + q4 * 8);
#pragma unroll
        for (int mi = 0; mi < 4; mi++)
#pragma unroll
            for (int ni = 0; ni < 4; ni++)
                acc[mi][ni] = __builtin_amdgcn_mfma_f32_16x16x32_f16(bf[ni], af[mi], acc[mi][ni], 0, 0, 0);
        __syncthreads();
    }
    // scale + bias; per-(row,wave) partials over this wave's 64 cols
    const float os = 1.f / 1024.f;
#pragma unroll
    for (int mi = 0; mi < 4; mi++) {
        float s = 0.f, ss = 0.f;
#pragma unroll
        for (int ni = 0; ni < 4; ni++) {
            float4 b4 = *(const float4*)(bias + w * 64 + ni * 16 + q4 * 4);
            const float* bp = &b4.x;
#pragma unroll
            for (int r = 0; r < 4; r++) {
                float v = acc[mi][ni][r] * os + bp[r];
                acc[mi][ni][r] = v;
                s += v; ss += v * v;
            }
        }
        s  += __shfl_xor(s, 16);  s  += __shfl_xor(s, 32);
        ss += __shfl_xor(ss, 16); ss += __shfl_xor(ss, 32);
        if (q4 == 0) {
            rs_sum[mi * 16 + lm][w] = s;
            rs_ssq[mi * 16 + lm][w] = ss;
        }
    }
    __syncthreads();
#pragma unroll
    for (int mi = 0; mi < 4; mi++) {
        int r64 = mi * 16 + lm;
        float s = 0.f, ss = 0.f;
#pragma unroll
        for (int k = 0; k < 8; k++) { s += rs_sum[r64][k]; ss += rs_ssq[r64][k]; }
        float mean = s * (1.f / 512.f);
        float var  = ss * (1.f / 512.f) - mean * mean;
        float rstd = rsqrtf(fmaxf(var, 0.f) + 1e-5f);
        int row = m0 + r64;
#pragma unroll
        for (int ni = 0; ni < 4; ni++) {
            int col0 = w * 64 + ni * 16 + q4 * 4;
            float4 sc4 = *(const float4*)(scale + col0);
            float4 x4  = *(const float4*)(x + (size_t)row * 512 + col0);
            const float* scp = &sc4.x; const float* xp = &x4.x;
            float4 o;
            float* op = &o.x;
#pragma unroll
            for (int r = 0; r < 4; r++)
                op[r] = (acc[mi][ni][r] - mean) * rstd * scp[r] + xp[r];
            *(float4*)(out + (size_t)row * 512 + col0) = o;
        }
    }
}

// ---------- launch ----------
extern "C" void kernel_launch(void* const* d_in, const int* in_sizes, int n_in,
                              void* d_out, int out_size, void* d_ws, size_t ws_size,
                              hipStream_t stream) {
    const float* x    = (const float*)d_in[0];
    const float* ln1s = (const float*)d_in[1];
    const float* wqkv = (const float*)d_in[2];
    const float* wout = (const float*)d_in[3];
    const float* bout = (const float*)d_in[4];
    const float* ln2s = (const float*)d_in[5];
    float* out = (float*)d_out;

    char* ws = (char*)d_ws;
    // ws layout (unchanged footprint):
    _Float16* wqkvT  = (_Float16*)(ws);                     // 1,572,864
    _Float16* woutT  = (_Float16*)(ws + 1572864);           //   524,288
    float*    Sbuf   = (float*)(ws + 6291456);              // [256][64] f32 : 64 KiB
    _Float16* normed = (_Float16*)(ws + 6356992);           // [32768][512] f16 : 32 MiB
    _Float16* attnF  = (_Float16*)(ws + 39911424);          // [32768][512] f16 : 32 MiB
    // d_out (64 MiB) is scratch until gemm_projln2: part2 dead after qattn.
    float* part2 = (float*)d_out;                           // [2][256][64][64] f32 : 8 MiB

    transpose_f2h<<<dim3(48, 16), 256, 0, stream>>>(wqkv, wqkvT, 512, 1536);
    transpose_f2h<<<dim3(16, 16), 256, 0, stream>>>(wout, woutT, 512, 512);
    ln1_kernel<<<8192, 256, 0, stream>>>(x, ln1s, normed);
    hipMemsetAsync(Sbuf, 0, 65536, stream);

    // kv GEMM + exp + S + ctx fused (no ekT/vT materialization)
    gemm_kvctx<<<dim3(2, 256), 512, 0, stream>>>(normed, wqkvT + 512 * 512, part2, Sbuf);
    // q = normed . w_qkv[:, 0:512] with fused softmax + PV (all batches)
    gemm_qattn<<<dim3(4, 256), 256, 0, stream>>>(normed, wqkvT, part2, Sbuf, attnF);
    // out = LN(attn . w_out^T / 1024 + b_out) * ln2_scale + x
    gemm_projln2<<<512, 512, 0, stream>>>(attnF, woutT, bout, x, ln2s, out);
}